// Round 4
// baseline (410.492 us; speedup 1.0000x reference)
//
#include <hip/hip_runtime.h>
#include <cstddef>

// LiteMLA: qkv GEMM (split-fp16 MFMA, 3-pass) -> dwconv5x5+groupmix ->
// linear attention -> proj GEMM (split-A fp16 MFMA, 2-pass) + BN.
// B=4, C=512, H=W=64, N=4096, heads=128, 24 ch/head.
//
// Precision design: attention's relu(q)/relu(k) sign decisions amplify GEMM
// rounding (bf16 1-pass -> absmax 0.07). Split fp16 (hi+lo) gives ~2^-22
// rel GEMM error on qkv; proj is linear so split-A only suffices.
//
// GEMM v5 (post-mortems R2+R3):
//  - R2 (v3) failed because per-iter A global loads were issued AFTER the
//    B-prefetch GLLs; vmcnt is IN-ORDER, so the A-wait drained the prefetch.
//  - R3 (v4, all-LDS dbuf) fixed stalls but 64KB LDS -> 2 blocks/CU and
//    LDS pipe (~2050cyc/iter) rivaled the matrix pipe (~1860cyc/iter).
//  v5: A (weights, L2-resident; consecutive blockIdx.x reuse the same rows)
//  loads DIRECT to VGPRs, issued at the TOP of each iter BEFORE the GLLs
//  (so the A-wait is vmcnt(#GLLs) and prefetch stays in flight). B hi/lo
//  stays in XOR-swizzled double-buffered LDS (conflicts measured 0).
//  LDS 32KB (qkv) / 16KB (proj); launch_bounds(256,3) -> 3 waves/SIMD.
//
// Workspace (peak 229 MiB):
//   qkv fp32     100663296 @ 0
//   y   fp32     100663296 @ 100663296
//   x_t_h fp16    16777216 @ 201326592  (dead after qkv GEMM)
//   x_t_l fp16    16777216 @ 218103808  (dead after qkv GEMM)
//   attout fp16   33554432 @ 201326592  (overlays x_t after it's dead)
//   w_qkv_h/l     1572864*2 @ 234881024
//   w_proj_h/l    1048576*2 @ 238026752
// vk stats (144 KB) live in d_out (proj GEMM fully overwrites d_out after).

#define NPIX 4096
#define TD3 1536

typedef _Float16 f16;
typedef __attribute__((ext_vector_type(8))) _Float16 v8h;
typedef __attribute__((ext_vector_type(4))) float v4f;
typedef unsigned short ushort_t;

#define GLL16(g, l) __builtin_amdgcn_global_load_lds(                         \
    (const __attribute__((address_space(1))) unsigned int*)(g),               \
    (__attribute__((address_space(3))) unsigned int*)(l), 16, 0, 0)

// ---------------------------------------------------------------------------
// Split fp16 MFMA GEMM. Ah/Al (M x K) row-major fp16 read DIRECT to regs
// (issued before prefetch each iter); Bh (and Bl if SPLITB) (N x K)
// row-major fp16 staged into double-buffered XOR-swizzled LDS; C (M x N)
// fp32. 128x128 tile, BK=32, 256 threads = 4 waves, each wave 64x64 via
// 4x4 grid of 16x16x32 MFMAs. C = Ah*Bh + Al*Bh (+ Ah*Bl if SPLITB).
//
// LDS swizzle (both-sides, rule #21): stage-side GLL dest linear, per-lane
// GLOBAL source computed from logical = phys ^ (((phys>>7)&3)<<4); read
// side slot = kq ^ ((rm>>1)&3). 16-lane quarter -> 8 distinct 16B slots x
// 2 lanes = conflict-free (verified R2: 6.29M -> 0).
// ---------------------------------------------------------------------------
template <int SPLITB, int BN>
__global__ __launch_bounds__(256, 3) void gemm_f16(
    const f16* __restrict__ Ah, const f16* __restrict__ Al,
    const f16* __restrict__ Bh, const f16* __restrict__ Bl,
    float* __restrict__ C, int M, int N, int K,
    const float* __restrict__ bn_g, const float* __restrict__ bn_b,
    const float* __restrict__ bn_m, const float* __restrict__ bn_v)
{
    __shared__ f16 BsH[2][128 * 32];
    __shared__ f16 BsL[SPLITB ? 2 : 1][SPLITB ? 128 * 32 : 64];

    const int tid  = threadIdx.x;
    const int lane = tid & 63;
    const int w    = tid >> 6;
    const int wm   = w >> 1, wn = w & 1;
    const int mBase = blockIdx.y * 128, nBase = blockIdx.x * 128;
    Bh += (size_t)blockIdx.z * N * K;
    if (SPLITB) Bl += (size_t)blockIdx.z * N * K;
    C  += (size_t)blockIdx.z * M * N;

    // B staging: 8 KB tile = 8 chunks of (64 lanes x 16 B); wave w does
    // chunks w*2, w*2+1. GLOBAL source pre-swizzled so linear GLL dest +
    // swizzled ds_read are consistent.
    const f16* gBh[2]; const f16* gBl[2];
    int ldsOff[2];
    #pragma unroll
    for (int p = 0; p < 2; ++p) {
        int phys = (w * 2 + p) * 1024 + lane * 16;     // byte offset in tile
        int lgc  = phys ^ (((phys >> 7) & 3) << 4);    // logical byte offset
        int r  = lgc >> 6;                             // row (64 B = 32 f16)
        int ci = (lgc & 63) >> 1;                      // f16 col index
        gBh[p] = Bh + (size_t)(nBase + r) * K + ci;
        if (SPLITB) gBl[p] = Bl + (size_t)(nBase + r) * K + ci;
        ldsOff[p] = (w * 2 + p) * 512;                 // f16 idx of chunk base
    }

    const int kq = lane >> 4;                 // k-chunk of 8
    const int rm = lane & 15;                 // row within 16
    const int slot = kq ^ ((rm >> 1) & 3);    // swizzled 16B slot for reads

    // A direct-load pointers (per-lane, per m-frag)
    const f16* pAh[4]; const f16* pAl[4];
    #pragma unroll
    for (int i = 0; i < 4; ++i) {
        size_t o = (size_t)(mBase + wm * 64 + i * 16 + rm) * K + kq * 8;
        pAh[i] = Ah + o;
        pAl[i] = Al + o;
    }

    v4f acc[4][4];
    #pragma unroll
    for (int i = 0; i < 4; ++i)
        #pragma unroll
        for (int j = 0; j < 4; ++j)
            acc[i][j] = (v4f){0.f, 0.f, 0.f, 0.f};

    const int KT = K >> 5;

    // prologue: stage B tile 0 into buf 0
    #pragma unroll
    for (int p = 0; p < 2; ++p) {
        GLL16(gBh[p], &BsH[0][ldsOff[p]]);
        if (SPLITB) GLL16(gBl[p], &BsL[0][ldsOff[p]]);
    }
    __syncthreads();

    for (int kt = 0; kt < KT; ++kt) {
        const int cb = kt & 1, nb = cb ^ 1;

        // 1) A fragments for THIS iter, issued FIRST (older than the GLLs
        //    below -> the MFMA's A-wait is vmcnt(#GLLs), prefetch stays in
        //    flight; this ordering is the v3-bug fix)
        v8h ah[4], al[4];
        #pragma unroll
        for (int i = 0; i < 4; ++i) {
            ah[i] = *(const v8h*)(pAh[i] + kt * 32);
            al[i] = *(const v8h*)(pAl[i] + kt * 32);
        }

        // 2) prefetch next B tile into the other buffer (drained only at
        //    the end-of-iter barrier, hidden under this iter's MFMAs)
        if (kt + 1 < KT) {
            #pragma unroll
            for (int p = 0; p < 2; ++p) {
                GLL16(gBh[p] + (kt + 1) * 32, &BsH[nb][ldsOff[p]]);
                if (SPLITB) GLL16(gBl[p] + (kt + 1) * 32, &BsL[nb][ldsOff[p]]);
            }
        }

        // 3) B fragments: swizzled LDS reads (conflict-free)
        v8h bh[4], bl[4];
        #pragma unroll
        for (int j = 0; j < 4; ++j) {
            int rowB = wn * 64 + j * 16 + rm;
            bh[j] = *(const v8h*)&BsH[cb][rowB * 32 + slot * 8];
            if (SPLITB)
                bl[j] = *(const v8h*)&BsL[cb][rowB * 32 + slot * 8];
        }

        // 4) MFMAs (same per-acc order as v2/v4 -> bit-identical output)
        #pragma unroll
        for (int i = 0; i < 4; ++i)
            #pragma unroll
            for (int j = 0; j < 4; ++j) {
                acc[i][j] = __builtin_amdgcn_mfma_f32_16x16x32_f16(
                    ah[i], bh[j], acc[i][j], 0, 0, 0);
                acc[i][j] = __builtin_amdgcn_mfma_f32_16x16x32_f16(
                    al[i], bh[j], acc[i][j], 0, 0, 0);
                if (SPLITB)
                    acc[i][j] = __builtin_amdgcn_mfma_f32_16x16x32_f16(
                        ah[i], bl[j], acc[i][j], 0, 0, 0);
            }
        __syncthreads();   // single barrier/iter: drains prefetch (issued
                           // before compute) + protects buffer swap
    }

    // epilogue: D row=(lane>>4)*4+reg, col=lane&15 (dtype-independent layout)
    const int rq = lane >> 4, cn = lane & 15;
    #pragma unroll
    for (int i = 0; i < 4; ++i) {
        #pragma unroll
        for (int rg = 0; rg < 4; ++rg) {
            int row = mBase + wm * 64 + i * 16 + rq * 4 + rg;
            float sc = 1.f, sh = 0.f;
            if (BN) {
                sc = bn_g[row] * rsqrtf(bn_v[row] + 1e-5f);
                sh = bn_b[row] - bn_m[row] * sc;
            }
            #pragma unroll
            for (int j = 0; j < 4; ++j) {
                int col = nBase + wn * 64 + j * 16 + cn;
                float v = acc[i][j][rg];
                C[(size_t)row * N + col] = BN ? (v * sc + sh) : v;
            }
        }
    }
}

// ---------------------------------------------------------------------------
// fp32 -> (fp16 hi, fp16 lo) elementwise. n4 = count/4.
// ---------------------------------------------------------------------------
__global__ __launch_bounds__(256) void cvt_split(
    const float* __restrict__ src, f16* __restrict__ dh, f16* __restrict__ dl,
    int n4)
{
    int i = blockIdx.x * 256 + threadIdx.x;
    if (i < n4) {
        float4 f = ((const float4*)src)[i];
        f16 h[4], l[4];
        float ff[4] = {f.x, f.y, f.z, f.w};
        #pragma unroll
        for (int q = 0; q < 4; ++q) {
            h[q] = (f16)ff[q];
            l[q] = (f16)(ff[q] - (float)h[q]);
        }
        *(uint2*)&dh[(size_t)i * 4] = *(uint2*)h;
        *(uint2*)&dl[(size_t)i * 4] = *(uint2*)l;
    }
}

// ---------------------------------------------------------------------------
// Transpose + split: x (b, c=512, n=4096) fp32 -> x_t_h/l (b, n, c) fp16.
// 64x64 tiles, 256 threads.
// ---------------------------------------------------------------------------
__global__ __launch_bounds__(256) void transp_split(
    const float* __restrict__ src, f16* __restrict__ dh, f16* __restrict__ dl)
{
    __shared__ float t[64][65];
    const int tid = threadIdx.x;
    const int n0 = blockIdx.x * 64, c0 = blockIdx.y * 64, b = blockIdx.z;

    const int row = tid >> 2;            // source channel within tile
    const int nn  = (tid & 3) * 16;      // 16 pixels per thread
    const float* sp = src + ((size_t)b * 512 + c0 + row) * NPIX + n0 + nn;
    #pragma unroll
    for (int q = 0; q < 4; ++q) {
        float4 f = *(const float4*)(sp + q * 4);
        t[row][nn + q * 4 + 0] = f.x;
        t[row][nn + q * 4 + 1] = f.y;
        t[row][nn + q * 4 + 2] = f.z;
        t[row][nn + q * 4 + 3] = f.w;
    }
    __syncthreads();

    const int nrow = tid >> 2;           // dst pixel within tile
    const int cc   = (tid & 3) * 16;     // 16 channels per thread
    f16 h[16], l[16];
    #pragma unroll
    for (int q = 0; q < 16; ++q) {
        float f = t[cc + q][nrow];
        h[q] = (f16)f;
        l[q] = (f16)(f - (float)h[q]);
    }
    size_t di = ((size_t)b * NPIX + n0 + nrow) * 512 + c0 + cc;
    *(uint4*)&dh[di] = *(uint4*)&h[0];
    *(uint4*)&dh[di + 8] = *(uint4*)&h[8];
    *(uint4*)&dl[di] = *(uint4*)&l[0];
    *(uint4*)&dl[di + 8] = *(uint4*)&l[8];
}

// ---------------------------------------------------------------------------
// Fused depthwise 5x5 conv (pad 2) + per-group 8x8 mix.
// V2: LDS-issue-bound fix. 32-row tile, each thread computes a 2x4 pixel
// block for all 8 channels via two aligned ds_read_b128 per (ch,row).
// wd/wp read from global with block-uniform addresses (scalar-load path).
// ---------------------------------------------------------------------------
__global__ __launch_bounds__(256) void dwpw(
    const float* __restrict__ qkv, const float* __restrict__ w_dw,
    const float* __restrict__ w_pw, float* __restrict__ y)
{
    __shared__ float tile[8][36][68];   // 78336 B -> 2 blocks/CU

    const int tid = threadIdx.x;
    const int g = blockIdx.y;
    const int b = blockIdx.z;
    const int h0 = blockIdx.x * 32;
    const size_t cbase = (size_t)b * TD3 + g * 8;

    // zero halo columns (global cols -2,-1 and 64,65 are image padding)
    for (int idx = tid; idx < 288; idx += 256) {
        int ch = idx / 36, r = idx - ch * 36;
        *(float2*)&tile[ch][r][0]  = (float2){0.f, 0.f};
        *(float2*)&tile[ch][r][66] = (float2){0.f, 0.f};
    }
    // interior: 8 ch x 36 rows x 16 float4 = 18 iters x 256 threads
    #pragma unroll
    for (int it = 0; it < 18; ++it) {
        int idx = tid + it * 256;
        int ch = idx / 576;
        int rem = idx - ch * 576;
        int r = rem >> 4, q = rem & 15;
        int gh = h0 + r - 2;
        float4 v = {0.f, 0.f, 0.f, 0.f};
        if (gh >= 0 && gh < 64)
            v = *(const float4*)&qkv[(cbase + ch) * NPIX + gh * 64 + q * 4];
        *(float2*)&tile[ch][r][2 + q * 4] = (float2){v.x, v.y};
        *(float2*)&tile[ch][r][4 + q * 4] = (float2){v.z, v.w};
    }
    __syncthreads();

    const int wc0 = (tid & 15) * 4;      // output cols wc0..wc0+3
    const int rp  = tid >> 4;            // output rows rp*2, rp*2+1 (local)

    float acc[8][8];                     // [out_ch][pixel: s*4+cc]
    #pragma unroll
    for (int o = 0; o < 8; ++o)
        #pragma unroll
        for (int p = 0; p < 8; ++p) acc[o][p] = 0.f;

    #pragma unroll
    for (int ch = 0; ch < 8; ++ch) {
        // per-channel weights: block-uniform global reads (scalar-loadable)
        const float* wdg = w_dw + (size_t)(g * 8 + ch) * 25;
        float wdr[25];
        #pragma unroll
        for (int t = 0; t < 25; ++t) wdr[t] = wdg[t];
        float wpr[8];
        #pragma unroll
        for (int o = 0; o < 8; ++o) wpr[o] = w_pw[g * 64 + o * 8 + ch];

        // 6 window rows x 8 cols, two aligned b128 each
        float w[6][8];
        #pragma unroll
        for (int rr = 0; rr < 6; ++rr) {
            *(float4*)&w[rr][0] = *(const float4*)&tile[ch][rp * 2 + rr][wc0];
            *(float4*)&w[rr][4] = *(const float4*)&tile[ch][rp * 2 + rr][wc0 + 4];
        }

        float dwv[8];
        #pragma unroll
        for (int s = 0; s < 2; ++s)
            #pragma unroll
            for (int cc = 0; cc < 4; ++cc) {
                float sum = 0.f;
                #pragma unroll
                for (int di = 0; di < 5; ++di)
                    #pragma unroll
                    for (int dj = 0; dj < 5; ++dj)
                        sum = fmaf(w[s + di][cc + dj], wdr[di * 5 + dj], sum);
                dwv[s * 4 + cc] = sum;
            }
        #pragma unroll
        for (int o = 0; o < 8; ++o)
            #pragma unroll
            for (int p = 0; p < 8; ++p)
                acc[o][p] = fmaf(dwv[p], wpr[o], acc[o][p]);
    }

    #pragma unroll
    for (int o = 0; o < 8; ++o)
        #pragma unroll
        for (int s = 0; s < 2; ++s) {
            float4 v = {acc[o][s * 4 + 0], acc[o][s * 4 + 1],
                        acc[o][s * 4 + 2], acc[o][s * 4 + 3]};
            *(float4*)&y[(cbase + o) * NPIX + (h0 + rp * 2 + s) * 64 + wc0] = v;
        }
}

// ---------------------------------------------------------------------------
// Attention stats per (b,h): vk[9][8] = sum_n [v;1][d,n] * relu(k)[e,n]
// ---------------------------------------------------------------------------
__global__ __launch_bounds__(256) void attn_stats(
    const float* __restrict__ qkv, const float* __restrict__ yy,
    float* __restrict__ vkout)
{
    const int h = blockIdx.x;
    const int b = blockIdx.y;
    const float* src = (h < 64)
        ? qkv + ((size_t)b * TD3 + h * 24) * NPIX
        : yy  + ((size_t)b * TD3 + (h - 64) * 24) * NPIX;

    float acc[9][8];
    #pragma unroll
    for (int d = 0; d < 9; ++d)
        #pragma unroll
        for (int e = 0; e < 8; ++e) acc[d][e] = 0.f;

    for (int n = threadIdx.x; n < NPIX; n += 256) {
        float kr[8], vv[8];
        #pragma unroll
        for (int e = 0; e < 8; ++e) kr[e] = fmaxf(src[(8 + e) * NPIX + n], 0.f);
        #pragma unroll
        for (int d = 0; d < 8; ++d) vv[d] = src[(16 + d) * NPIX + n];
        #pragma unroll
        for (int d = 0; d < 8; ++d)
            #pragma unroll
            for (int e = 0; e < 8; ++e) acc[d][e] = fmaf(vv[d], kr[e], acc[d][e]);
        #pragma unroll
        for (int e = 0; e < 8; ++e) acc[8][e] += kr[e];
    }

    __shared__ float part[4][72];
    const int lane = threadIdx.x & 63, wave = threadIdx.x >> 6;
    #pragma unroll
    for (int i = 0; i < 72; ++i) {
        float v = acc[i / 8][i % 8];
        #pragma unroll
        for (int off = 32; off; off >>= 1) v += __shfl_down(v, off, 64);
        if (lane == 0) part[wave][i] = v;
    }
    __syncthreads();
    if (threadIdx.x < 72) {
        float v = part[0][threadIdx.x] + part[1][threadIdx.x] +
                  part[2][threadIdx.x] + part[3][threadIdx.x];
        vkout[((size_t)b * 128 + h) * 72 + threadIdx.x] = v;
    }
}

// ---------------------------------------------------------------------------
// Attention apply: out[d,n] = (sum_e vk[d][e] rq[e]) / (sum_e vk[8][e] rq[e]+eps)
// Writes DIRECTLY transposed as fp16: attout[(b*4096+n)*1024 + h*8 + d].
// ---------------------------------------------------------------------------
__global__ __launch_bounds__(256) void attn_apply_t(
    const float* __restrict__ qkv, const float* __restrict__ yy,
    const float* __restrict__ vkin, f16* __restrict__ attout)
{
    const int h = blockIdx.y;
    const int b = blockIdx.z;
    const int n = blockIdx.x * 256 + threadIdx.x;

    __shared__ float vk[72];
    if (threadIdx.x < 72)
        vk[threadIdx.x] = vkin[((size_t)b * 128 + h) * 72 + threadIdx.x];
    __syncthreads();

    const float* src = (h < 64)
        ? qkv + ((size_t)b * TD3 + h * 24) * NPIX
        : yy  + ((size_t)b * TD3 + (h - 64) * 24) * NPIX;

    float qr[8];
    #pragma unroll
    for (int e = 0; e < 8; ++e) qr[e] = fmaxf(src[e * NPIX + n], 0.f);

    float den = 0.f;
    #pragma unroll
    for (int e = 0; e < 8; ++e) den = fmaf(vk[64 + e], qr[e], den);
    float inv = 1.f / (den + 1e-15f);

    f16 o[8];
    #pragma unroll
    for (int d = 0; d < 8; ++d) {
        float num = 0.f;
        #pragma unroll
        for (int e = 0; e < 8; ++e) num = fmaf(vk[d * 8 + e], qr[e], num);
        o[d] = (f16)(num * inv);
    }
    *(uint4*)&attout[((size_t)b * NPIX + n) * 1024 + h * 8] = *(uint4*)o;
}

// ---------------------------------------------------------------------------
extern "C" void kernel_launch(void* const* d_in, const int* in_sizes, int n_in,
                              void* d_out, int out_size, void* d_ws, size_t ws_size,
                              hipStream_t stream)
{
    (void)in_sizes; (void)n_in; (void)out_size; (void)ws_size;
    const float* x      = (const float*)d_in[0];
    const float* w_qkv  = (const float*)d_in[1];
    const float* w_dw   = (const float*)d_in[2];
    const float* w_pw   = (const float*)d_in[3];
    const float* w_proj = (const float*)d_in[4];
    const float* bn_g   = (const float*)d_in[5];
    const float* bn_b   = (const float*)d_in[6];
    const float* bn_m   = (const float*)d_in[7];
    const float* bn_v   = (const float*)d_in[8];
    float* out = (float*)d_out;

    char* ws = (char*)d_ws;
    float* qkv     = (float*)(ws);
    float* y       = (float*)(ws + 100663296);
    f16*   x_t_h   = (f16*)(ws + 201326592);    // dead after qkv GEMM
    f16*   x_t_l   = (f16*)(ws + 218103808);    // dead after qkv GEMM
    f16*   attout  = (f16*)(ws + 201326592);    // overlays x_t_h/l
    f16*   w_qkv_h = (f16*)(ws + 234881024);
    f16*   w_qkv_l = (f16*)(ws + 236453888);
    f16*   w_proj_h= (f16*)(ws + 238026752);
    f16*   w_proj_l= (f16*)(ws + 239075328);
    float* vk      = out;                        // scratch; proj overwrites

    // 0. split weights to fp16 hi/lo
    cvt_split<<<768, 256, 0, stream>>>(w_qkv, w_qkv_h, w_qkv_l, 196608);
    cvt_split<<<512, 256, 0, stream>>>(w_proj, w_proj_h, w_proj_l, 131072);
    // 1. x (b,c,n) -> x_t (b,n,c) fp16 hi/lo
    transp_split<<<dim3(64, 8, 4), 256, 0, stream>>>(x, x_t_h, x_t_l);
    // 2. qkv = w_qkv @ x  (M=1536,N=4096,K=512, batch 4), 3-pass split
    gemm_f16<1, 0><<<dim3(32, 12, 4), 256, 0, stream>>>(
        w_qkv_h, w_qkv_l, x_t_h, x_t_l, qkv, 1536, 4096, 512,
        nullptr, nullptr, nullptr, nullptr);
    // 3. y = groupmix(dwconv5x5(qkv)), 32-row tiles
    dwpw<<<dim3(2, 192, 4), 256, 0, stream>>>(qkv, w_dw, w_pw, y);
    // 4. attention stats -> vk (in d_out)
    attn_stats<<<dim3(128, 4), 256, 0, stream>>>(qkv, y, vk);
    // 5. attention apply -> attout (b,n,c) fp16 (overwrites dead x_t region)
    attn_apply_t<<<dim3(16, 128, 4), 256, 0, stream>>>(qkv, y, vk, attout);
    // 6. out = BN(w_proj @ attout)  (M=512,N=4096,K=1024, batch 4), 2-pass
    gemm_f16<0, 1><<<dim3(32, 4, 4), 256, 0, stream>>>(
        w_proj_h, w_proj_l, attout, nullptr, out, 512, 4096, 1024,
        bn_g, bn_b, bn_m, bn_v);
}

// Round 5
// 368.052 us; speedup vs baseline: 1.1153x; 1.1153x over previous
//
#include <hip/hip_runtime.h>
#include <cstddef>

// LiteMLA: qkv GEMM (split-fp16 MFMA, 3-pass) -> dwconv5x5+groupmix ->
// linear attention -> proj GEMM (split-A fp16 MFMA, 2-pass) + BN.
// B=4, C=512, H=W=64, N=4096, heads=128, 24 ch/head.
//
// Precision design: attention's relu(q)/relu(k) sign decisions amplify GEMM
// rounding (bf16 1-pass -> absmax 0.07). Split fp16 (hi+lo) gives ~2^-22
// rel GEMM error on qkv; proj is linear so split-A only suffices.
//
// GEMM v6 (post-mortems R2-R4):
//  - A-direct-from-global (v3/v5) fails: hipcc reorders the A loads after
//    the B-prefetch GLLs; vmcnt is in-order -> prefetch drained on the
//    critical path (MfmaUtil 25%). Twice confirmed. Abandoned.
//  - v4 (all-LDS, swizzle, dbuf, 1 barrier/iter) = 924 TF, LDS-traffic
//    bound: 96KB LDS traffic per block-iter vs ~466cyc MFMA (MfmaUtil 40%).
//  v6 keeps the v4 schedule EXACTLY but raises arithmetic intensity per
//  LDS byte: block tile 128x256, wave tile 64x128 (acc 4x8; A-frags reused
//  8x instead of 4x; B-frags transient inside the j-loop to cap VGPRs).
//  Normalized LDS traffic drops 25%; MfmaUtil ceiling ~60%.
//
// Workspace (peak 229 MiB):
//   qkv fp32     100663296 @ 0
//   y   fp32     100663296 @ 100663296
//   x_t_h fp16    16777216 @ 201326592  (dead after qkv GEMM)
//   x_t_l fp16    16777216 @ 218103808  (dead after qkv GEMM)
//   attout fp16   33554432 @ 201326592  (overlays x_t after it's dead)
//   w_qkv_h/l     1572864*2 @ 234881024
//   w_proj_h/l    1048576*2 @ 238026752
// vk stats (144 KB) live in d_out (proj GEMM fully overwrites d_out after).

#define NPIX 4096
#define TD3 1536

typedef _Float16 f16;
typedef __attribute__((ext_vector_type(8))) _Float16 v8h;
typedef __attribute__((ext_vector_type(4))) float v4f;
typedef unsigned short ushort_t;

#define GLL16(g, l) __builtin_amdgcn_global_load_lds(                         \
    (const __attribute__((address_space(1))) unsigned int*)(g),               \
    (__attribute__((address_space(3))) unsigned int*)(l), 16, 0, 0)

// ---------------------------------------------------------------------------
// Split fp16 MFMA GEMM. Ah/Al (M x K) row-major fp16, Bh (and Bl if SPLITB)
// (N x K) row-major fp16, all staged into DOUBLE-BUFFERED XOR-SWIZZLED LDS;
// C (M x N) fp32. 128x256 tile, BK=32, 256 threads = 4 waves (2M x 2N),
// each wave 64x128 via 4x8 grid of 16x16x32 MFMAs.
// C = Ah*Bh + Al*Bh (+ Ah*Bl if SPLITB). BN epilogue optional.
//
// LDS swizzle (both-sides, rule #21): stage-side GLL dest linear, per-lane
// GLOBAL source computed from logical = phys ^ (((phys>>7)&3)<<4); read
// side slot = kq ^ ((rm>>1)&3). 16-lane quarter -> 8 distinct 16B slots x
// 2 lanes = conflict-free (verified R2/R3: 6.29M -> 0).
//
// Schedule (v4-proven): prologue stage tile0->buf0, barrier; each iter:
// issue GLL prefetch(t+1)->buf^1 FIRST, ds_read buf[t], MFMA, ONE
// __syncthreads (drains prefetch under the 96 MFMAs issued since).
// ---------------------------------------------------------------------------
template <int SPLITB, int BN>
__global__ __launch_bounds__(256, 1) void gemm_f16(
    const f16* __restrict__ Ah, const f16* __restrict__ Al,
    const f16* __restrict__ Bh, const f16* __restrict__ Bl,
    float* __restrict__ C, int M, int N, int K,
    const float* __restrict__ bn_g, const float* __restrict__ bn_b,
    const float* __restrict__ bn_m, const float* __restrict__ bn_v)
{
    __shared__ f16 AsH[2][128 * 32];
    __shared__ f16 AsL[2][128 * 32];
    __shared__ f16 BsH[2][256 * 32];
    __shared__ f16 BsL[SPLITB ? 2 : 1][SPLITB ? 256 * 32 : 64];

    const int tid  = threadIdx.x;
    const int lane = tid & 63;
    const int w    = tid >> 6;
    const int wm   = w >> 1, wn = w & 1;
    const int mBase = blockIdx.y * 128, nBase = blockIdx.x * 256;
    Bh += (size_t)blockIdx.z * N * K;
    if (SPLITB) Bl += (size_t)blockIdx.z * N * K;
    C  += (size_t)blockIdx.z * M * N;

    // A staging: 8 KB tile = 8 chunks of (64 lanes x 16 B); wave w does
    // chunks w*2, w*2+1. B staging: 16 KB tile = 16 chunks; wave w does
    // chunks w*4..w*4+3. GLOBAL source pre-swizzled so linear GLL dest +
    // swizzled ds_read are consistent. Offsets kept as 32-bit f16 indices.
    int aOff[2], bOff[4];     // global f16 index (without kt*32)
    int ldsA[2], ldsB[4];     // f16 index of chunk base in LDS tile
    #pragma unroll
    for (int p = 0; p < 2; ++p) {
        int phys = (w * 2 + p) * 1024 + lane * 16;     // byte offset in tile
        int lgc  = phys ^ (((phys >> 7) & 3) << 4);    // logical byte offset
        int r  = lgc >> 6;                             // row (64 B = 32 f16)
        int ci = (lgc & 63) >> 1;                      // f16 col index
        aOff[p] = (mBase + r) * K + ci;
        ldsA[p] = (w * 2 + p) * 512;
    }
    #pragma unroll
    for (int p = 0; p < 4; ++p) {
        int phys = (w * 4 + p) * 1024 + lane * 16;
        int lgc  = phys ^ (((phys >> 7) & 3) << 4);
        int r  = lgc >> 6;                             // row 0..255
        int ci = (lgc & 63) >> 1;
        bOff[p] = (nBase + r) * K + ci;
        ldsB[p] = (w * 4 + p) * 512;
    }

    const int kq = lane >> 4;                 // k-chunk of 8
    const int rm = lane & 15;                 // row within 16
    const int slot = kq ^ ((rm >> 1) & 3);    // swizzled 16B slot for reads

    v4f acc[4][8];
    #pragma unroll
    for (int i = 0; i < 4; ++i)
        #pragma unroll
        for (int j = 0; j < 8; ++j)
            acc[i][j] = (v4f){0.f, 0.f, 0.f, 0.f};

    const int KT = K >> 5;

    // prologue: stage tile 0 into buf 0
    #pragma unroll
    for (int p = 0; p < 2; ++p) {
        GLL16(Ah + aOff[p], &AsH[0][ldsA[p]]);
        GLL16(Al + aOff[p], &AsL[0][ldsA[p]]);
    }
    #pragma unroll
    for (int p = 0; p < 4; ++p) {
        GLL16(Bh + bOff[p], &BsH[0][ldsB[p]]);
        if (SPLITB) GLL16(Bl + bOff[p], &BsL[0][ldsB[p]]);
    }
    __syncthreads();

    for (int kt = 0; kt < KT; ++kt) {
        const int cb = kt & 1, nb = cb ^ 1;
        // prefetch next tile into the other buffer; drained only at the
        // end-of-iter barrier (hidden under this iter's 96 MFMAs)
        if (kt + 1 < KT) {
            const int ko = (kt + 1) * 32;
            #pragma unroll
            for (int p = 0; p < 2; ++p) {
                GLL16(Ah + aOff[p] + ko, &AsH[nb][ldsA[p]]);
                GLL16(Al + aOff[p] + ko, &AsL[nb][ldsA[p]]);
            }
            #pragma unroll
            for (int p = 0; p < 4; ++p) {
                GLL16(Bh + bOff[p] + ko, &BsH[nb][ldsB[p]]);
                if (SPLITB) GLL16(Bl + bOff[p] + ko, &BsL[nb][ldsB[p]]);
            }
        }

        // A fragments for the whole iter (reused across 8 j's)
        v8h ah[4], al[4];
        #pragma unroll
        for (int i = 0; i < 4; ++i) {
            int rowA = wm * 64 + i * 16 + rm;
            ah[i] = *(const v8h*)&AsH[cb][rowA * 32 + slot * 8];
            al[i] = *(const v8h*)&AsL[cb][rowA * 32 + slot * 8];
        }
        // B fragments transient per j (caps VGPR; 12 MFMAs per read pair)
        #pragma unroll
        for (int j = 0; j < 8; ++j) {
            int rowB = wn * 128 + j * 16 + rm;
            v8h bh = *(const v8h*)&BsH[cb][rowB * 32 + slot * 8];
            v8h bl;
            if (SPLITB)
                bl = *(const v8h*)&BsL[cb][rowB * 32 + slot * 8];
            #pragma unroll
            for (int i = 0; i < 4; ++i) {
                acc[i][j] = __builtin_amdgcn_mfma_f32_16x16x32_f16(
                    ah[i], bh, acc[i][j], 0, 0, 0);
                acc[i][j] = __builtin_amdgcn_mfma_f32_16x16x32_f16(
                    al[i], bh, acc[i][j], 0, 0, 0);
                if (SPLITB)
                    acc[i][j] = __builtin_amdgcn_mfma_f32_16x16x32_f16(
                        ah[i], bl, acc[i][j], 0, 0, 0);
            }
        }
        __syncthreads();   // single barrier/iter: drains prefetch (issued
                           // before compute) + protects buffer swap
    }

    // epilogue: D row=(lane>>4)*4+reg, col=lane&15 (dtype-independent layout)
    const int rq = lane >> 4, cn = lane & 15;
    #pragma unroll
    for (int i = 0; i < 4; ++i) {
        #pragma unroll
        for (int rg = 0; rg < 4; ++rg) {
            int row = mBase + wm * 64 + i * 16 + rq * 4 + rg;
            float sc = 1.f, sh = 0.f;
            if (BN) {
                sc = bn_g[row] * rsqrtf(bn_v[row] + 1e-5f);
                sh = bn_b[row] - bn_m[row] * sc;
            }
            #pragma unroll
            for (int j = 0; j < 8; ++j) {
                int col = nBase + wn * 128 + j * 16 + cn;
                float v = acc[i][j][rg];
                C[(size_t)row * N + col] = BN ? (v * sc + sh) : v;
            }
        }
    }
}

// ---------------------------------------------------------------------------
// fp32 -> (fp16 hi, fp16 lo) elementwise for BOTH weight tensors in one
// launch. n4_1 / n4_2 = counts/4 for the two tensors.
// ---------------------------------------------------------------------------
__global__ __launch_bounds__(256) void cvt_split2(
    const float* __restrict__ s1, f16* __restrict__ d1h, f16* __restrict__ d1l,
    int n4_1,
    const float* __restrict__ s2, f16* __restrict__ d2h, f16* __restrict__ d2l,
    int n4_2)
{
    int i = blockIdx.x * 256 + threadIdx.x;
    const float* src; f16* dh; f16* dl; int idx;
    if (i < n4_1) { src = s1; dh = d1h; dl = d1l; idx = i; }
    else if (i < n4_1 + n4_2) { src = s2; dh = d2h; dl = d2l; idx = i - n4_1; }
    else return;
    float4 f = ((const float4*)src)[idx];
    f16 h[4], l[4];
    float ff[4] = {f.x, f.y, f.z, f.w};
    #pragma unroll
    for (int q = 0; q < 4; ++q) {
        h[q] = (f16)ff[q];
        l[q] = (f16)(ff[q] - (float)h[q]);
    }
    *(uint2*)&dh[(size_t)idx * 4] = *(uint2*)h;
    *(uint2*)&dl[(size_t)idx * 4] = *(uint2*)l;
}

// ---------------------------------------------------------------------------
// Transpose + split: x (b, c=512, n=4096) fp32 -> x_t_h/l (b, n, c) fp16.
// 64x64 tiles, 256 threads.
// ---------------------------------------------------------------------------
__global__ __launch_bounds__(256) void transp_split(
    const float* __restrict__ src, f16* __restrict__ dh, f16* __restrict__ dl)
{
    __shared__ float t[64][65];
    const int tid = threadIdx.x;
    const int n0 = blockIdx.x * 64, c0 = blockIdx.y * 64, b = blockIdx.z;

    const int row = tid >> 2;            // source channel within tile
    const int nn  = (tid & 3) * 16;      // 16 pixels per thread
    const float* sp = src + ((size_t)b * 512 + c0 + row) * NPIX + n0 + nn;
    #pragma unroll
    for (int q = 0; q < 4; ++q) {
        float4 f = *(const float4*)(sp + q * 4);
        t[row][nn + q * 4 + 0] = f.x;
        t[row][nn + q * 4 + 1] = f.y;
        t[row][nn + q * 4 + 2] = f.z;
        t[row][nn + q * 4 + 3] = f.w;
    }
    __syncthreads();

    const int nrow = tid >> 2;           // dst pixel within tile
    const int cc   = (tid & 3) * 16;     // 16 channels per thread
    f16 h[16], l[16];
    #pragma unroll
    for (int q = 0; q < 16; ++q) {
        float f = t[cc + q][nrow];
        h[q] = (f16)f;
        l[q] = (f16)(f - (float)h[q]);
    }
    size_t di = ((size_t)b * NPIX + n0 + nrow) * 512 + c0 + cc;
    *(uint4*)&dh[di] = *(uint4*)&h[0];
    *(uint4*)&dh[di + 8] = *(uint4*)&h[8];
    *(uint4*)&dl[di] = *(uint4*)&l[0];
    *(uint4*)&dl[di + 8] = *(uint4*)&l[8];
}

// ---------------------------------------------------------------------------
// Fused depthwise 5x5 conv (pad 2) + per-group 8x8 mix.
// V2: LDS-issue-bound fix. 32-row tile, each thread computes a 2x4 pixel
// block for all 8 channels via two aligned ds_read_b128 per (ch,row).
// wd/wp read from global with block-uniform addresses (scalar-load path).
// ---------------------------------------------------------------------------
__global__ __launch_bounds__(256) void dwpw(
    const float* __restrict__ qkv, const float* __restrict__ w_dw,
    const float* __restrict__ w_pw, float* __restrict__ y)
{
    __shared__ float tile[8][36][68];   // 78336 B -> 2 blocks/CU

    const int tid = threadIdx.x;
    const int g = blockIdx.y;
    const int b = blockIdx.z;
    const int h0 = blockIdx.x * 32;
    const size_t cbase = (size_t)b * TD3 + g * 8;

    // zero halo columns (global cols -2,-1 and 64,65 are image padding)
    for (int idx = tid; idx < 288; idx += 256) {
        int ch = idx / 36, r = idx - ch * 36;
        *(float2*)&tile[ch][r][0]  = (float2){0.f, 0.f};
        *(float2*)&tile[ch][r][66] = (float2){0.f, 0.f};
    }
    // interior: 8 ch x 36 rows x 16 float4 = 18 iters x 256 threads
    #pragma unroll
    for (int it = 0; it < 18; ++it) {
        int idx = tid + it * 256;
        int ch = idx / 576;
        int rem = idx - ch * 576;
        int r = rem >> 4, q = rem & 15;
        int gh = h0 + r - 2;
        float4 v = {0.f, 0.f, 0.f, 0.f};
        if (gh >= 0 && gh < 64)
            v = *(const float4*)&qkv[(cbase + ch) * NPIX + gh * 64 + q * 4];
        *(float2*)&tile[ch][r][2 + q * 4] = (float2){v.x, v.y};
        *(float2*)&tile[ch][r][4 + q * 4] = (float2){v.z, v.w};
    }
    __syncthreads();

    const int wc0 = (tid & 15) * 4;      // output cols wc0..wc0+3
    const int rp  = tid >> 4;            // output rows rp*2, rp*2+1 (local)

    float acc[8][8];                     // [out_ch][pixel: s*4+cc]
    #pragma unroll
    for (int o = 0; o < 8; ++o)
        #pragma unroll
        for (int p = 0; p < 8; ++p) acc[o][p] = 0.f;

    #pragma unroll
    for (int ch = 0; ch < 8; ++ch) {
        // per-channel weights: block-uniform global reads (scalar-loadable)
        const float* wdg = w_dw + (size_t)(g * 8 + ch) * 25;
        float wdr[25];
        #pragma unroll
        for (int t = 0; t < 25; ++t) wdr[t] = wdg[t];
        float wpr[8];
        #pragma unroll
        for (int o = 0; o < 8; ++o) wpr[o] = w_pw[g * 64 + o * 8 + ch];

        // 6 window rows x 8 cols, two aligned b128 each
        float w[6][8];
        #pragma unroll
        for (int rr = 0; rr < 6; ++rr) {
            *(float4*)&w[rr][0] = *(const float4*)&tile[ch][rp * 2 + rr][wc0];
            *(float4*)&w[rr][4] = *(const float4*)&tile[ch][rp * 2 + rr][wc0 + 4];
        }

        float dwv[8];
        #pragma unroll
        for (int s = 0; s < 2; ++s)
            #pragma unroll
            for (int cc = 0; cc < 4; ++cc) {
                float sum = 0.f;
                #pragma unroll
                for (int di = 0; di < 5; ++di)
                    #pragma unroll
                    for (int dj = 0; dj < 5; ++dj)
                        sum = fmaf(w[s + di][cc + dj], wdr[di * 5 + dj], sum);
                dwv[s * 4 + cc] = sum;
            }
        #pragma unroll
        for (int o = 0; o < 8; ++o)
            #pragma unroll
            for (int p = 0; p < 8; ++p)
                acc[o][p] = fmaf(dwv[p], wpr[o], acc[o][p]);
    }

    #pragma unroll
    for (int o = 0; o < 8; ++o)
        #pragma unroll
        for (int s = 0; s < 2; ++s) {
            float4 v = {acc[o][s * 4 + 0], acc[o][s * 4 + 1],
                        acc[o][s * 4 + 2], acc[o][s * 4 + 3]};
            *(float4*)&y[(cbase + o) * NPIX + (h0 + rp * 2 + s) * 64 + wc0] = v;
        }
}

// ---------------------------------------------------------------------------
// Attention stats per (b,h): vk[9][8] = sum_n [v;1][d,n] * relu(k)[e,n]
// ---------------------------------------------------------------------------
__global__ __launch_bounds__(256) void attn_stats(
    const float* __restrict__ qkv, const float* __restrict__ yy,
    float* __restrict__ vkout)
{
    const int h = blockIdx.x;
    const int b = blockIdx.y;
    const float* src = (h < 64)
        ? qkv + ((size_t)b * TD3 + h * 24) * NPIX
        : yy  + ((size_t)b * TD3 + (h - 64) * 24) * NPIX;

    float acc[9][8];
    #pragma unroll
    for (int d = 0; d < 9; ++d)
        #pragma unroll
        for (int e = 0; e < 8; ++e) acc[d][e] = 0.f;

    for (int n = threadIdx.x; n < NPIX; n += 256) {
        float kr[8], vv[8];
        #pragma unroll
        for (int e = 0; e < 8; ++e) kr[e] = fmaxf(src[(8 + e) * NPIX + n], 0.f);
        #pragma unroll
        for (int d = 0; d < 8; ++d) vv[d] = src[(16 + d) * NPIX + n];
        #pragma unroll
        for (int d = 0; d < 8; ++d)
            #pragma unroll
            for (int e = 0; e < 8; ++e) acc[d][e] = fmaf(vv[d], kr[e], acc[d][e]);
        #pragma unroll
        for (int e = 0; e < 8; ++e) acc[8][e] += kr[e];
    }

    __shared__ float part[4][72];
    const int lane = threadIdx.x & 63, wave = threadIdx.x >> 6;
    #pragma unroll
    for (int i = 0; i < 72; ++i) {
        float v = acc[i / 8][i % 8];
        #pragma unroll
        for (int off = 32; off; off >>= 1) v += __shfl_down(v, off, 64);
        if (lane == 0) part[wave][i] = v;
    }
    __syncthreads();
    if (threadIdx.x < 72) {
        float v = part[0][threadIdx.x] + part[1][threadIdx.x] +
                  part[2][threadIdx.x] + part[3][threadIdx.x];
        vkout[((size_t)b * 128 + h) * 72 + threadIdx.x] = v;
    }
}

// ---------------------------------------------------------------------------
// Attention apply: out[d,n] = (sum_e vk[d][e] rq[e]) / (sum_e vk[8][e] rq[e]+eps)
// Writes DIRECTLY transposed as fp16: attout[(b*4096+n)*1024 + h*8 + d].
// ---------------------------------------------------------------------------
__global__ __launch_bounds__(256) void attn_apply_t(
    const float* __restrict__ qkv, const float* __restrict__ yy,
    const float* __restrict__ vkin, f16* __restrict__ attout)
{
    const int h = blockIdx.y;
    const int b = blockIdx.z;
    const int n = blockIdx.x * 256 + threadIdx.x;

    __shared__ float vk[72];
    if (threadIdx.x < 72)
        vk[threadIdx.x] = vkin[((size_t)b * 128 + h) * 72 + threadIdx.x];
    __syncthreads();

    const float* src = (h < 64)
        ? qkv + ((size_t)b * TD3 + h * 24) * NPIX
        : yy  + ((size_t)b * TD3 + (h - 64) * 24) * NPIX;

    float qr[8];
    #pragma unroll
    for (int e = 0; e < 8; ++e) qr[e] = fmaxf(src[e * NPIX + n], 0.f);

    float den = 0.f;
    #pragma unroll
    for (int e = 0; e < 8; ++e) den = fmaf(vk[64 + e], qr[e], den);
    float inv = 1.f / (den + 1e-15f);

    f16 o[8];
    #pragma unroll
    for (int d = 0; d < 8; ++d) {
        float num = 0.f;
        #pragma unroll
        for (int e = 0; e < 8; ++e) num = fmaf(vk[d * 8 + e], qr[e], num);
        o[d] = (f16)(num * inv);
    }
    *(uint4*)&attout[((size_t)b * NPIX + n) * 1024 + h * 8] = *(uint4*)o;
}

// ---------------------------------------------------------------------------
extern "C" void kernel_launch(void* const* d_in, const int* in_sizes, int n_in,
                              void* d_out, int out_size, void* d_ws, size_t ws_size,
                              hipStream_t stream)
{
    (void)in_sizes; (void)n_in; (void)out_size; (void)ws_size;
    const float* x      = (const float*)d_in[0];
    const float* w_qkv  = (const float*)d_in[1];
    const float* w_dw   = (const float*)d_in[2];
    const float* w_pw   = (const float*)d_in[3];
    const float* w_proj = (const float*)d_in[4];
    const float* bn_g   = (const float*)d_in[5];
    const float* bn_b   = (const float*)d_in[6];
    const float* bn_m   = (const float*)d_in[7];
    const float* bn_v   = (const float*)d_in[8];
    float* out = (float*)d_out;

    char* ws = (char*)d_ws;
    float* qkv     = (float*)(ws);
    float* y       = (float*)(ws + 100663296);
    f16*   x_t_h   = (f16*)(ws + 201326592);    // dead after qkv GEMM
    f16*   x_t_l   = (f16*)(ws + 218103808);    // dead after qkv GEMM
    f16*   attout  = (f16*)(ws + 201326592);    // overlays x_t_h/l
    f16*   w_qkv_h = (f16*)(ws + 234881024);
    f16*   w_qkv_l = (f16*)(ws + 236453888);
    f16*   w_proj_h= (f16*)(ws + 238026752);
    f16*   w_proj_l= (f16*)(ws + 239075328);
    float* vk      = out;                        // scratch; proj overwrites

    // 0. split both weight tensors to fp16 hi/lo (one launch)
    cvt_split2<<<1280, 256, 0, stream>>>(
        w_qkv, w_qkv_h, w_qkv_l, 196608,
        w_proj, w_proj_h, w_proj_l, 131072);
    // 1. x (b,c,n) -> x_t (b,n,c) fp16 hi/lo
    transp_split<<<dim3(64, 8, 4), 256, 0, stream>>>(x, x_t_h, x_t_l);
    // 2. qkv = w_qkv @ x  (M=1536,N=4096,K=512, batch 4), 3-pass split
    gemm_f16<1, 0><<<dim3(16, 12, 4), 256, 0, stream>>>(
        w_qkv_h, w_qkv_l, x_t_h, x_t_l, qkv, 1536, 4096, 512,
        nullptr, nullptr, nullptr, nullptr);
    // 3. y = groupmix(dwconv5x5(qkv)), 32-row tiles
    dwpw<<<dim3(2, 192, 4), 256, 0, stream>>>(qkv, w_dw, w_pw, y);
    // 4. attention stats -> vk (in d_out)
    attn_stats<<<dim3(128, 4), 256, 0, stream>>>(qkv, y, vk);
    // 5. attention apply -> attout (b,n,c) fp16 (overwrites dead x_t region)
    attn_apply_t<<<dim3(16, 128, 4), 256, 0, stream>>>(qkv, y, vk, attout);
    // 6. out = BN(w_proj @ attout)  (M=512,N=4096,K=1024, batch 4), 2-pass
    gemm_f16<0, 1><<<dim3(16, 4, 4), 256, 0, stream>>>(
        w_proj_h, w_proj_l, attout, nullptr, out, 512, 4096, 1024,
        bn_g, bn_b, bn_m, bn_v);
}

// Round 6
// 349.811 us; speedup vs baseline: 1.1735x; 1.0521x over previous
//
#include <hip/hip_runtime.h>
#include <cstddef>

// LiteMLA: qkv GEMM (split-fp16 MFMA, 3-pass) -> dwconv5x5+groupmix ->
// linear attention -> proj GEMM (split-A fp16 MFMA, 2-pass) + BN.
// B=4, C=512, H=W=64, N=4096, heads=128, 24 ch/head.
//
// Precision design: attention's relu(q)/relu(k) sign decisions amplify GEMM
// rounding (bf16 1-pass -> absmax 0.07). Split fp16 (hi+lo) gives ~2^-22
// rel GEMM error on qkv; proj is linear so split-A only suffices.
//
// GEMM v7 (post-mortems R2-R5): the 2-phase drain-0 structure ceilings at
// ~920 TF no matter the tile (R3=84us@40%Mfma; R5 bigger tile = worse via
// 1blk/CU drain exposure). v7 applies T4 (counted vmcnt, never drain):
//  - 3-slot LDS ring of BK=32 K-tiles; 512 thr / 8 waves, BM=256 BN=128,
//    wave-tile 64x64 (v4's proven inner loop).
//  - per iter: s_waitcnt vmcnt(L) [L=loads/thread/tile; in-order retire =>
//    tile t landed, t+1 stays IN FLIGHT] -> raw s_barrier -> sched_barrier
//    -> issue GLLs for t+2 -> swizzled ds_read t -> MFMA. vmcnt never 0.
//  - ring safety: slot(t+2) last read in iter t-1; those reads complete
//    (lgkm forced by their MFMAs) before barrier(t). Uniform 6 GLL/thread.
//  - same per-C accumulation order as v4 => bit-identical (absmax is the
//    race detector: must stay 0.00390625).
//
// Workspace (peak 229 MiB):
//   qkv fp32     100663296 @ 0
//   y   fp32     100663296 @ 100663296
//   x_t_h fp16    16777216 @ 201326592  (dead after qkv GEMM)
//   x_t_l fp16    16777216 @ 218103808  (dead after qkv GEMM)
//   attout fp16   33554432 @ 201326592  (overlays x_t after it's dead)
//   w_qkv_h/l     1572864*2 @ 234881024
//   w_proj_h/l    1048576*2 @ 238026752
// vk stats (144 KB) live in d_out (proj GEMM fully overwrites d_out after).

#define NPIX 4096
#define TD3 1536

typedef _Float16 f16;
typedef __attribute__((ext_vector_type(8))) _Float16 v8h;
typedef __attribute__((ext_vector_type(4))) float v4f;
typedef unsigned short ushort_t;

#define GLL16(g, l) __builtin_amdgcn_global_load_lds(                         \
    (const __attribute__((address_space(1))) unsigned int*)(g),               \
    (__attribute__((address_space(3))) unsigned int*)(l), 16, 0, 0)

#define WAIT_VM(n) asm volatile("s_waitcnt vmcnt(" #n ")" ::: "memory")

// ---------------------------------------------------------------------------
// Split fp16 MFMA GEMM, ring-3 counted-vmcnt pipeline.
// Ah/Al (M x K) row-major fp16, Bh (and Bl if SPLITB) (N x K) row-major
// fp16, staged into a 3-slot XOR-SWIZZLED LDS ring; C (M x N) fp32.
// 256x128 tile, BK=32, 512 threads = 8 waves (4M x 2N), wave 64x64 via
// 4x4 grid of 16x16x32 MFMAs. C = Ah*Bh + Al*Bh (+ Ah*Bl if SPLITB).
//
// LDS swizzle (both-sides, rule #21, verified R2/R3: conflicts 6.29M -> 0):
// stage-side GLL dest linear, per-lane GLOBAL source computed from
// logical = phys ^ (((phys>>7)&3)<<4); read side slot = kq ^ ((rm>>1)&3).
// ---------------------------------------------------------------------------
template <int SPLITB, int BN>
__global__ __launch_bounds__(512, 1) void gemm_f16(
    const f16* __restrict__ Ah, const f16* __restrict__ Al,
    const f16* __restrict__ Bh, const f16* __restrict__ Bl,
    float* __restrict__ C, int M, int N, int K,
    const float* __restrict__ bn_g, const float* __restrict__ bn_b,
    const float* __restrict__ bn_m, const float* __restrict__ bn_v)
{
    __shared__ f16 AsH[3][256 * 32];                       // 48 KB
    __shared__ f16 AsL[3][256 * 32];                       // 48 KB
    __shared__ f16 BsH[3][128 * 32];                       // 24 KB
    __shared__ f16 BsL[SPLITB ? 3 : 1][SPLITB ? 128 * 32 : 32]; // 24 KB / 64 B

    const int tid  = threadIdx.x;
    const int lane = tid & 63;
    const int w    = tid >> 6;            // 0..7
    const int wm   = w >> 1, wn = w & 1;  // 4 waves in M, 2 in N
    const int mBase = blockIdx.y * 256, nBase = blockIdx.x * 128;
    Bh += (size_t)blockIdx.z * N * K;
    if (SPLITB) Bl += (size_t)blockIdx.z * N * K;
    C  += (size_t)blockIdx.z * M * N;

    // Staging split: A tile 16 KB = 16 chunks of (64 lanes x 16 B), wave w
    // does chunks w*2,w*2+1; B tile 8 KB = 8 chunks, wave w does chunk w.
    // GLOBAL source pre-swizzled so linear GLL dest + swizzled read agree.
    int aOff[2], ldsA[2];
    #pragma unroll
    for (int p = 0; p < 2; ++p) {
        int phys = (w * 2 + p) * 1024 + lane * 16;     // byte offset in tile
        int lgc  = phys ^ (((phys >> 7) & 3) << 4);    // logical byte offset
        int r  = lgc >> 6;                             // row (64 B = 32 f16)
        int ci = (lgc & 63) >> 1;                      // f16 col index
        aOff[p] = (mBase + r) * K + ci;
        ldsA[p] = (w * 2 + p) * 512;
    }
    int physB = w * 1024 + lane * 16;
    int lgcB  = physB ^ (((physB >> 7) & 3) << 4);
    const int bOff = (nBase + (lgcB >> 6)) * K + ((lgcB & 63) >> 1);
    const int ldsB = w * 512;

    const int kq = lane >> 4;                 // k-chunk of 8
    const int rm = lane & 15;                 // row within 16
    const int slot = kq ^ ((rm >> 1) & 3);    // swizzled 16B slot for reads

    v4f acc[4][4];
    #pragma unroll
    for (int i = 0; i < 4; ++i)
        #pragma unroll
        for (int j = 0; j < 4; ++j)
            acc[i][j] = (v4f){0.f, 0.f, 0.f, 0.f};

    const int KT = K >> 5;

    // per-tile stage: 6 (SPLITB) / 5 GLLs per thread, uniform across waves
    auto stage = [&](int kt, int s) {
        const int ko = kt * 32;
        GLL16(Ah + aOff[0] + ko, &AsH[s][ldsA[0]]);
        GLL16(Ah + aOff[1] + ko, &AsH[s][ldsA[1]]);
        GLL16(Al + aOff[0] + ko, &AsL[s][ldsA[0]]);
        GLL16(Al + aOff[1] + ko, &AsL[s][ldsA[1]]);
        GLL16(Bh + bOff + ko, &BsH[s][ldsB]);
        if (SPLITB) GLL16(Bl + bOff + ko, &BsL[s][ldsB]);
    };

    // prologue: tiles 0,1 into slots 0,1 (2L loads in flight)
    stage(0, 0);
    stage(1, 1);

    for (int kt = 0; kt < KT; ++kt) {
        const int cs = kt % 3;
        // counted wait: keep tile t+1's L loads IN FLIGHT, ensure tile t
        // landed (vmcnt retires in order). Never 0 in the main loop.
        if (kt < KT - 1) {
            if (SPLITB) WAIT_VM(6); else WAIT_VM(5);
        } else {
            WAIT_VM(0);
        }
        __builtin_amdgcn_s_barrier();      // raw barrier: NO implicit drain
        __builtin_amdgcn_sched_barrier(0); // pin: nothing hoists above

        if (kt + 2 < KT) stage(kt + 2, (kt + 2) % 3);

        // fragments: swizzled LDS reads (conflict-free), lgkm-only waits
        v8h ah[4], al[4], bh[4], bl[4];
        #pragma unroll
        for (int i = 0; i < 4; ++i) {
            int rowA = wm * 64 + i * 16 + rm;
            int rowB = wn * 64 + i * 16 + rm;
            ah[i] = *(const v8h*)&AsH[cs][rowA * 32 + slot * 8];
            al[i] = *(const v8h*)&AsL[cs][rowA * 32 + slot * 8];
            bh[i] = *(const v8h*)&BsH[cs][rowB * 32 + slot * 8];
            if (SPLITB)
                bl[i] = *(const v8h*)&BsL[cs][rowB * 32 + slot * 8];
        }
        #pragma unroll
        for (int i = 0; i < 4; ++i)
            #pragma unroll
            for (int j = 0; j < 4; ++j) {
                acc[i][j] = __builtin_amdgcn_mfma_f32_16x16x32_f16(
                    ah[i], bh[j], acc[i][j], 0, 0, 0);
                acc[i][j] = __builtin_amdgcn_mfma_f32_16x16x32_f16(
                    al[i], bh[j], acc[i][j], 0, 0, 0);
                if (SPLITB)
                    acc[i][j] = __builtin_amdgcn_mfma_f32_16x16x32_f16(
                        ah[i], bl[j], acc[i][j], 0, 0, 0);
            }
        __builtin_amdgcn_sched_barrier(0); // iter fence: no cross-iter motion
    }

    // epilogue: D row=(lane>>4)*4+reg, col=lane&15 (dtype-independent layout)
    const int rq = lane >> 4, cn = lane & 15;
    #pragma unroll
    for (int i = 0; i < 4; ++i) {
        #pragma unroll
        for (int rg = 0; rg < 4; ++rg) {
            int row = mBase + wm * 64 + i * 16 + rq * 4 + rg;
            float sc = 1.f, sh = 0.f;
            if (BN) {
                sc = bn_g[row] * rsqrtf(bn_v[row] + 1e-5f);
                sh = bn_b[row] - bn_m[row] * sc;
            }
            #pragma unroll
            for (int j = 0; j < 4; ++j) {
                int col = nBase + wn * 64 + j * 16 + cn;
                float v = acc[i][j][rg];
                C[(size_t)row * N + col] = BN ? (v * sc + sh) : v;
            }
        }
    }
}

// ---------------------------------------------------------------------------
// fp32 -> (fp16 hi, fp16 lo) elementwise for BOTH weight tensors in one
// launch. n4_1 / n4_2 = counts/4 for the two tensors.
// ---------------------------------------------------------------------------
__global__ __launch_bounds__(256) void cvt_split2(
    const float* __restrict__ s1, f16* __restrict__ d1h, f16* __restrict__ d1l,
    int n4_1,
    const float* __restrict__ s2, f16* __restrict__ d2h, f16* __restrict__ d2l,
    int n4_2)
{
    int i = blockIdx.x * 256 + threadIdx.x;
    const float* src; f16* dh; f16* dl; int idx;
    if (i < n4_1) { src = s1; dh = d1h; dl = d1l; idx = i; }
    else if (i < n4_1 + n4_2) { src = s2; dh = d2h; dl = d2l; idx = i - n4_1; }
    else return;
    float4 f = ((const float4*)src)[idx];
    f16 h[4], l[4];
    float ff[4] = {f.x, f.y, f.z, f.w};
    #pragma unroll
    for (int q = 0; q < 4; ++q) {
        h[q] = (f16)ff[q];
        l[q] = (f16)(ff[q] - (float)h[q]);
    }
    *(uint2*)&dh[(size_t)idx * 4] = *(uint2*)h;
    *(uint2*)&dl[(size_t)idx * 4] = *(uint2*)l;
}

// ---------------------------------------------------------------------------
// Transpose + split: x (b, c=512, n=4096) fp32 -> x_t_h/l (b, n, c) fp16.
// 64x64 tiles, 256 threads.
// ---------------------------------------------------------------------------
__global__ __launch_bounds__(256) void transp_split(
    const float* __restrict__ src, f16* __restrict__ dh, f16* __restrict__ dl)
{
    __shared__ float t[64][65];
    const int tid = threadIdx.x;
    const int n0 = blockIdx.x * 64, c0 = blockIdx.y * 64, b = blockIdx.z;

    const int row = tid >> 2;            // source channel within tile
    const int nn  = (tid & 3) * 16;      // 16 pixels per thread
    const float* sp = src + ((size_t)b * 512 + c0 + row) * NPIX + n0 + nn;
    #pragma unroll
    for (int q = 0; q < 4; ++q) {
        float4 f = *(const float4*)(sp + q * 4);
        t[row][nn + q * 4 + 0] = f.x;
        t[row][nn + q * 4 + 1] = f.y;
        t[row][nn + q * 4 + 2] = f.z;
        t[row][nn + q * 4 + 3] = f.w;
    }
    __syncthreads();

    const int nrow = tid >> 2;           // dst pixel within tile
    const int cc   = (tid & 3) * 16;     // 16 channels per thread
    f16 h[16], l[16];
    #pragma unroll
    for (int q = 0; q < 16; ++q) {
        float f = t[cc + q][nrow];
        h[q] = (f16)f;
        l[q] = (f16)(f - (float)h[q]);
    }
    size_t di = ((size_t)b * NPIX + n0 + nrow) * 512 + c0 + cc;
    *(uint4*)&dh[di] = *(uint4*)&h[0];
    *(uint4*)&dh[di + 8] = *(uint4*)&h[8];
    *(uint4*)&dl[di] = *(uint4*)&l[0];
    *(uint4*)&dl[di + 8] = *(uint4*)&l[8];
}

// ---------------------------------------------------------------------------
// Fused depthwise 5x5 conv (pad 2) + per-group 8x8 mix.
// V2: LDS-issue-bound fix. 32-row tile, each thread computes a 2x4 pixel
// block for all 8 channels via two aligned ds_read_b128 per (ch,row).
// wd/wp read from global with block-uniform addresses (scalar-load path).
// ---------------------------------------------------------------------------
__global__ __launch_bounds__(256) void dwpw(
    const float* __restrict__ qkv, const float* __restrict__ w_dw,
    const float* __restrict__ w_pw, float* __restrict__ y)
{
    __shared__ float tile[8][36][68];   // 78336 B -> 2 blocks/CU

    const int tid = threadIdx.x;
    const int g = blockIdx.y;
    const int b = blockIdx.z;
    const int h0 = blockIdx.x * 32;
    const size_t cbase = (size_t)b * TD3 + g * 8;

    // zero halo columns (global cols -2,-1 and 64,65 are image padding)
    for (int idx = tid; idx < 288; idx += 256) {
        int ch = idx / 36, r = idx - ch * 36;
        *(float2*)&tile[ch][r][0]  = (float2){0.f, 0.f};
        *(float2*)&tile[ch][r][66] = (float2){0.f, 0.f};
    }
    // interior: 8 ch x 36 rows x 16 float4 = 18 iters x 256 threads
    #pragma unroll
    for (int it = 0; it < 18; ++it) {
        int idx = tid + it * 256;
        int ch = idx / 576;
        int rem = idx - ch * 576;
        int r = rem >> 4, q = rem & 15;
        int gh = h0 + r - 2;
        float4 v = {0.f, 0.f, 0.f, 0.f};
        if (gh >= 0 && gh < 64)
            v = *(const float4*)&qkv[(cbase + ch) * NPIX + gh * 64 + q * 4];
        *(float2*)&tile[ch][r][2 + q * 4] = (float2){v.x, v.y};
        *(float2*)&tile[ch][r][4 + q * 4] = (float2){v.z, v.w};
    }
    __syncthreads();

    const int wc0 = (tid & 15) * 4;      // output cols wc0..wc0+3
    const int rp  = tid >> 4;            // output rows rp*2, rp*2+1 (local)

    float acc[8][8];                     // [out_ch][pixel: s*4+cc]
    #pragma unroll
    for (int o = 0; o < 8; ++o)
        #pragma unroll
        for (int p = 0; p < 8; ++p) acc[o][p] = 0.f;

    #pragma unroll
    for (int ch = 0; ch < 8; ++ch) {
        // per-channel weights: block-uniform global reads (scalar-loadable)
        const float* wdg = w_dw + (size_t)(g * 8 + ch) * 25;
        float wdr[25];
        #pragma unroll
        for (int t = 0; t < 25; ++t) wdr[t] = wdg[t];
        float wpr[8];
        #pragma unroll
        for (int o = 0; o < 8; ++o) wpr[o] = w_pw[g * 64 + o * 8 + ch];

        // 6 window rows x 8 cols, two aligned b128 each
        float w[6][8];
        #pragma unroll
        for (int rr = 0; rr < 6; ++rr) {
            *(float4*)&w[rr][0] = *(const float4*)&tile[ch][rp * 2 + rr][wc0];
            *(float4*)&w[rr][4] = *(const float4*)&tile[ch][rp * 2 + rr][wc0 + 4];
        }

        float dwv[8];
        #pragma unroll
        for (int s = 0; s < 2; ++s)
            #pragma unroll
            for (int cc = 0; cc < 4; ++cc) {
                float sum = 0.f;
                #pragma unroll
                for (int di = 0; di < 5; ++di)
                    #pragma unroll
                    for (int dj = 0; dj < 5; ++dj)
                        sum = fmaf(w[s + di][cc + dj], wdr[di * 5 + dj], sum);
                dwv[s * 4 + cc] = sum;
            }
        #pragma unroll
        for (int o = 0; o < 8; ++o)
            #pragma unroll
            for (int p = 0; p < 8; ++p)
                acc[o][p] = fmaf(dwv[p], wpr[o], acc[o][p]);
    }

    #pragma unroll
    for (int o = 0; o < 8; ++o)
        #pragma unroll
        for (int s = 0; s < 2; ++s) {
            float4 v = {acc[o][s * 4 + 0], acc[o][s * 4 + 1],
                        acc[o][s * 4 + 2], acc[o][s * 4 + 3]};
            *(float4*)&y[(cbase + o) * NPIX + (h0 + rp * 2 + s) * 64 + wc0] = v;
        }
}

// ---------------------------------------------------------------------------
// Attention stats per (b,h): vk[9][8] = sum_n [v;1][d,n] * relu(k)[e,n]
// ---------------------------------------------------------------------------
__global__ __launch_bounds__(256) void attn_stats(
    const float* __restrict__ qkv, const float* __restrict__ yy,
    float* __restrict__ vkout)
{
    const int h = blockIdx.x;
    const int b = blockIdx.y;
    const float* src = (h < 64)
        ? qkv + ((size_t)b * TD3 + h * 24) * NPIX
        : yy  + ((size_t)b * TD3 + (h - 64) * 24) * NPIX;

    float acc[9][8];
    #pragma unroll
    for (int d = 0; d < 9; ++d)
        #pragma unroll
        for (int e = 0; e < 8; ++e) acc[d][e] = 0.f;

    for (int n = threadIdx.x; n < NPIX; n += 256) {
        float kr[8], vv[8];
        #pragma unroll
        for (int e = 0; e < 8; ++e) kr[e] = fmaxf(src[(8 + e) * NPIX + n], 0.f);
        #pragma unroll
        for (int d = 0; d < 8; ++d) vv[d] = src[(16 + d) * NPIX + n];
        #pragma unroll
        for (int d = 0; d < 8; ++d)
            #pragma unroll
            for (int e = 0; e < 8; ++e) acc[d][e] = fmaf(vv[d], kr[e], acc[d][e]);
        #pragma unroll
        for (int e = 0; e < 8; ++e) acc[8][e] += kr[e];
    }

    __shared__ float part[4][72];
    const int lane = threadIdx.x & 63, wave = threadIdx.x >> 6;
    #pragma unroll
    for (int i = 0; i < 72; ++i) {
        float v = acc[i / 8][i % 8];
        #pragma unroll
        for (int off = 32; off; off >>= 1) v += __shfl_down(v, off, 64);
        if (lane == 0) part[wave][i] = v;
    }
    __syncthreads();
    if (threadIdx.x < 72) {
        float v = part[0][threadIdx.x] + part[1][threadIdx.x] +
                  part[2][threadIdx.x] + part[3][threadIdx.x];
        vkout[((size_t)b * 128 + h) * 72 + threadIdx.x] = v;
    }
}

// ---------------------------------------------------------------------------
// Attention apply: out[d,n] = (sum_e vk[d][e] rq[e]) / (sum_e vk[8][e] rq[e]+eps)
// Writes DIRECTLY transposed as fp16: attout[(b*4096+n)*1024 + h*8 + d].
// ---------------------------------------------------------------------------
__global__ __launch_bounds__(256) void attn_apply_t(
    const float* __restrict__ qkv, const float* __restrict__ yy,
    const float* __restrict__ vkin, f16* __restrict__ attout)
{
    const int h = blockIdx.y;
    const int b = blockIdx.z;
    const int n = blockIdx.x * 256 + threadIdx.x;

    __shared__ float vk[72];
    if (threadIdx.x < 72)
        vk[threadIdx.x] = vkin[((size_t)b * 128 + h) * 72 + threadIdx.x];
    __syncthreads();

    const float* src = (h < 64)
        ? qkv + ((size_t)b * TD3 + h * 24) * NPIX
        : yy  + ((size_t)b * TD3 + (h - 64) * 24) * NPIX;

    float qr[8];
    #pragma unroll
    for (int e = 0; e < 8; ++e) qr[e] = fmaxf(src[e * NPIX + n], 0.f);

    float den = 0.f;
    #pragma unroll
    for (int e = 0; e < 8; ++e) den = fmaf(vk[64 + e], qr[e], den);
    float inv = 1.f / (den + 1e-15f);

    f16 o[8];
    #pragma unroll
    for (int d = 0; d < 8; ++d) {
        float num = 0.f;
        #pragma unroll
        for (int e = 0; e < 8; ++e) num = fmaf(vk[d * 8 + e], qr[e], num);
        o[d] = (f16)(num * inv);
    }
    *(uint4*)&attout[((size_t)b * NPIX + n) * 1024 + h * 8] = *(uint4*)o;
}

// ---------------------------------------------------------------------------
extern "C" void kernel_launch(void* const* d_in, const int* in_sizes, int n_in,
                              void* d_out, int out_size, void* d_ws, size_t ws_size,
                              hipStream_t stream)
{
    (void)in_sizes; (void)n_in; (void)out_size; (void)ws_size;
    const float* x      = (const float*)d_in[0];
    const float* w_qkv  = (const float*)d_in[1];
    const float* w_dw   = (const float*)d_in[2];
    const float* w_pw   = (const float*)d_in[3];
    const float* w_proj = (const float*)d_in[4];
    const float* bn_g   = (const float*)d_in[5];
    const float* bn_b   = (const float*)d_in[6];
    const float* bn_m   = (const float*)d_in[7];
    const float* bn_v   = (const float*)d_in[8];
    float* out = (float*)d_out;

    char* ws = (char*)d_ws;
    float* qkv     = (float*)(ws);
    float* y       = (float*)(ws + 100663296);
    f16*   x_t_h   = (f16*)(ws + 201326592);    // dead after qkv GEMM
    f16*   x_t_l   = (f16*)(ws + 218103808);    // dead after qkv GEMM
    f16*   attout  = (f16*)(ws + 201326592);    // overlays x_t_h/l
    f16*   w_qkv_h = (f16*)(ws + 234881024);
    f16*   w_qkv_l = (f16*)(ws + 236453888);
    f16*   w_proj_h= (f16*)(ws + 238026752);
    f16*   w_proj_l= (f16*)(ws + 239075328);
    float* vk      = out;                        // scratch; proj overwrites

    // 0. split both weight tensors to fp16 hi/lo (one launch)
    cvt_split2<<<1280, 256, 0, stream>>>(
        w_qkv, w_qkv_h, w_qkv_l, 196608,
        w_proj, w_proj_h, w_proj_l, 131072);
    // 1. x (b,c,n) -> x_t (b,n,c) fp16 hi/lo
    transp_split<<<dim3(64, 8, 4), 256, 0, stream>>>(x, x_t_h, x_t_l);
    // 2. qkv = w_qkv @ x  (M=1536,N=4096,K=512, batch 4), 3-pass split
    gemm_f16<1, 0><<<dim3(32, 6, 4), 512, 0, stream>>>(
        w_qkv_h, w_qkv_l, x_t_h, x_t_l, qkv, 1536, 4096, 512,
        nullptr, nullptr, nullptr, nullptr);
    // 3. y = groupmix(dwconv5x5(qkv)), 32-row tiles
    dwpw<<<dim3(2, 192, 4), 256, 0, stream>>>(qkv, w_dw, w_pw, y);
    // 4. attention stats -> vk (in d_out)
    attn_stats<<<dim3(128, 4), 256, 0, stream>>>(qkv, y, vk);
    // 5. attention apply -> attout (b,n,c) fp16 (overwrites dead x_t region)
    attn_apply_t<<<dim3(16, 128, 4), 256, 0, stream>>>(qkv, y, vk, attout);
    // 6. out = BN(w_proj @ attout)  (M=512,N=4096,K=1024, batch 4), 2-pass
    gemm_f16<0, 1><<<dim3(32, 2, 4), 512, 0, stream>>>(
        w_proj_h, w_proj_l, attout, nullptr, out, 512, 4096, 1024,
        bn_g, bn_b, bn_m, bn_v);
}

// Round 8
// 324.668 us; speedup vs baseline: 1.2643x; 1.0774x over previous
//
#include <hip/hip_runtime.h>
#include <cstddef>

// LiteMLA: qkv GEMM (split-fp16 MFMA, 3-pass) -> dwconv5x5+groupmix ->
// linear attention -> proj GEMM (split-A fp16 MFMA, 2-pass) + BN.
// B=4, C=512, H=W=64, N=4096, heads=128, 24 ch/head.
//
// Precision design: attention's relu(q)/relu(k) sign decisions amplify GEMM
// rounding (bf16 1-pass -> absmax 0.07). Split fp16 (hi+lo) gives ~2^-22
// rel GEMM error on qkv; proj is linear so split-A only suffices.
//
// GEMM v8 (post-mortem R6; R7 bench was an infra failure, kernel never ran):
// counted-vmcnt ring works (absmax parity, 0 conflicts) and R6 hit exactly
// its LDS-feed ceiling (MfmaUtil 33% = MFMA 1860cyc vs LDS 1570cyc +
// lockstep 1blk/CU). R3 beat it only via 2 desynced blocks/CU. v8:
// (1) bigger wave tiles for FLOP/LDS-byte, (2) LDS <= 80KB/block =>
// 2 blocks/CU, (3) counted-vmcnt ring-2.
//  - gemm_qkv: 192x128 blk, 4 waves, wave 96x64, ring-2 = 80KB exactly,
//    10 GLL/thread -> WAIT_VM(10) steady (never drain). MFMA:LDS = 1.22.
//  - gemm_proj: 128x256 blk, 4 waves, wave 64x128, ring-2 = 64KB,
//    WAIT_VM(8). Grid = 256 blocks = exactly 1 round. MFMA:LDS = 1.45.
// Same per-element MFMA order as R3/R6 -> bit-identical (absmax is the race
// detector: must stay 0.00390625).
//
// Workspace (peak 229 MiB): qkv fp32 @0; y fp32 @100663296; x_t_h/l fp16
// @201326592/@218103808 (dead after qkv GEMM); attout fp16 @201326592
// (overlays x_t); w_qkv_h/l @234881024; w_proj_h/l @238026752.
// vk stats (144 KB) live in d_out (proj GEMM fully overwrites d_out after).

#define NPIX 4096
#define TD3 1536

typedef _Float16 f16;
typedef __attribute__((ext_vector_type(8))) _Float16 v8h;
typedef __attribute__((ext_vector_type(4))) float v4f;

#define GLL16(g, l) __builtin_amdgcn_global_load_lds(                         \
    (const __attribute__((address_space(1))) unsigned int*)(g),               \
    (__attribute__((address_space(3))) unsigned int*)(l), 16, 0, 0)

#define WAIT_VM(n) asm volatile("s_waitcnt vmcnt(" #n ")" ::: "memory")
#define WAIT_LGKM0() asm volatile("s_waitcnt lgkmcnt(0)" ::: "memory")
#define SBAR() __builtin_amdgcn_s_barrier()
#define SCHED() __builtin_amdgcn_sched_barrier(0)

// ---------------------------------------------------------------------------
// qkv GEMM: C = Ah*Bh + Al*Bh + Ah*Bl. A=w_qkv (1536x512) hi/lo, B=x_t
// (4096x512) hi/lo, C (1536x4096) fp32, batched over z.
// 192x128 block, BK=32, 256 thr = 4 waves (2M x 2N), wave 96x64 (acc 6x4).
// Ring-2 XOR-swizzled LDS (80 KB) + counted vmcnt (10 GLL/thread/tile).
// Schedule/iter: WAIT_VM(10) -> barrier -> 20 ds_reads -> lgkmcnt(0) ->
// barrier -> stage(t+2) -> 72 MFMAs. vmcnt never 0 until the last iter.
// ---------------------------------------------------------------------------
__global__ __launch_bounds__(256, 2) void gemm_qkv(
    const f16* __restrict__ Ah, const f16* __restrict__ Al,
    const f16* __restrict__ Bh, const f16* __restrict__ Bl,
    float* __restrict__ C)
{
    const int N = 4096, K = 512, KT = 16;
    __shared__ f16 AsH[2][192 * 32];   // 24 KB
    __shared__ f16 AsL[2][192 * 32];   // 24 KB
    __shared__ f16 BsH[2][128 * 32];   // 16 KB
    __shared__ f16 BsL[2][128 * 32];   // 16 KB  => 80 KB total

    const int tid = threadIdx.x;
    const int lane = tid & 63;
    const int w = tid >> 6;
    const int wm = w >> 1, wn = w & 1;
    const int mBase = blockIdx.y * 192, nBase = blockIdx.x * 128;
    Bh += (size_t)blockIdx.z * N * K;
    Bl += (size_t)blockIdx.z * N * K;
    C  += (size_t)blockIdx.z * 1536 * N;

    // staging chunks (1 KB = 64 lanes x 16B). A: 12 chunks, wave w gets
    // w*3..w*3+2; B: 8 chunks, wave w gets w*2,w*2+1. GLOBAL source is
    // pre-swizzled (logical = phys ^ (((phys>>7)&3)<<4)) so the linear GLL
    // dest + swizzled ds_read agree (rule #21; verified R2/R3/R6).
    int aOff[3], ldsA[3], bOff[2], ldsB[2];
    #pragma unroll
    for (int p = 0; p < 3; ++p) {
        int c = w * 3 + p;
        int phys = c * 1024 + lane * 16;
        int lgc = phys ^ (((phys >> 7) & 3) << 4);
        aOff[p] = (mBase + (lgc >> 6)) * K + ((lgc & 63) >> 1);
        ldsA[p] = c * 512;
    }
    #pragma unroll
    for (int p = 0; p < 2; ++p) {
        int c = w * 2 + p;
        int phys = c * 1024 + lane * 16;
        int lgc = phys ^ (((phys >> 7) & 3) << 4);
        bOff[p] = (nBase + (lgc >> 6)) * K + ((lgc & 63) >> 1);
        ldsB[p] = c * 512;
    }

    const int kq = lane >> 4, rm = lane & 15;
    const int slot = kq ^ ((rm >> 1) & 3);   // conflict-free read slot

    v4f acc[6][4];
    #pragma unroll
    for (int i = 0; i < 6; ++i)
        #pragma unroll
        for (int j = 0; j < 4; ++j)
            acc[i][j] = (v4f){0.f, 0.f, 0.f, 0.f};

    auto stage = [&](int kt, int s) {
        const int ko = kt * 32;
        #pragma unroll
        for (int p = 0; p < 3; ++p) {
            GLL16(Ah + aOff[p] + ko, &AsH[s][ldsA[p]]);
            GLL16(Al + aOff[p] + ko, &AsL[s][ldsA[p]]);
        }
        #pragma unroll
        for (int p = 0; p < 2; ++p) {
            GLL16(Bh + bOff[p] + ko, &BsH[s][ldsB[p]]);
            GLL16(Bl + bOff[p] + ko, &BsL[s][ldsB[p]]);
        }
    };
    stage(0, 0);
    stage(1, 1);      // 20 loads in flight

    for (int kt = 0; kt < KT; ++kt) {
        const int cs = kt & 1;
        // tile t landed; tile t+1's 10 loads stay IN FLIGHT (per-wave,
        // in-order retirement; each wave counts only its own loads)
        if (kt < KT - 1) { WAIT_VM(10); } else { WAIT_VM(0); }
        SBAR(); SCHED();

        v8h ah[6], al[6], bh[4], bl[4];
        #pragma unroll
        for (int i = 0; i < 6; ++i) {
            int rA = (wm * 96 + i * 16 + rm) * 32 + slot * 8;
            ah[i] = *(const v8h*)&AsH[cs][rA];
            al[i] = *(const v8h*)&AsL[cs][rA];
        }
        #pragma unroll
        for (int j = 0; j < 4; ++j) {
            int rB = (wn * 64 + j * 16 + rm) * 32 + slot * 8;
            bh[j] = *(const v8h*)&BsH[cs][rB];
            bl[j] = *(const v8h*)&BsL[cs][rB];
        }
        WAIT_LGKM0(); SCHED();
        SBAR(); SCHED();          // all waves' reads of slot cs complete

        if (kt + 2 < KT) stage(kt + 2, cs);   // overwrite cs; lands >=300cyc
                                              // later, under the MFMAs below
        #pragma unroll
        for (int i = 0; i < 6; ++i)
            #pragma unroll
            for (int j = 0; j < 4; ++j) {
                acc[i][j] = __builtin_amdgcn_mfma_f32_16x16x32_f16(
                    ah[i], bh[j], acc[i][j], 0, 0, 0);
                acc[i][j] = __builtin_amdgcn_mfma_f32_16x16x32_f16(
                    al[i], bh[j], acc[i][j], 0, 0, 0);
                acc[i][j] = __builtin_amdgcn_mfma_f32_16x16x32_f16(
                    ah[i], bl[j], acc[i][j], 0, 0, 0);
            }
        SCHED();
    }

    // epilogue: D row=(lane>>4)*4+reg, col=lane&15
    const int rq = lane >> 4, cn = lane & 15;
    #pragma unroll
    for (int i = 0; i < 6; ++i)
        #pragma unroll
        for (int rg = 0; rg < 4; ++rg) {
            int row = mBase + wm * 96 + i * 16 + rq * 4 + rg;
            #pragma unroll
            for (int j = 0; j < 4; ++j) {
                int col = nBase + wn * 64 + j * 16 + cn;
                C[(size_t)row * N + col] = acc[i][j][rg];
            }
        }
}

// ---------------------------------------------------------------------------
// proj GEMM + BN: C = BN(Ah*Bh + Al*Bh). A=w_proj (512x1024) hi/lo,
// B=attout (4096x1024) fp16, C (512x4096) fp32, batched over z.
// 128x256 block, BK=32, 256 thr = 4 waves (2M x 2N), wave 64x128 (acc 4x8).
// Ring-2 LDS (64 KB), WAIT_VM(8). Grid 16x4x4 = 256 blocks = 1 round.
// ---------------------------------------------------------------------------
__global__ __launch_bounds__(256, 2) void gemm_proj(
    const f16* __restrict__ Ah, const f16* __restrict__ Al,
    const f16* __restrict__ Bh, float* __restrict__ C,
    const float* __restrict__ bn_g, const float* __restrict__ bn_b,
    const float* __restrict__ bn_m, const float* __restrict__ bn_v)
{
    const int N = 4096, K = 1024, KT = 32;
    __shared__ f16 AsH[2][128 * 32];   // 16 KB
    __shared__ f16 AsL[2][128 * 32];   // 16 KB
    __shared__ f16 BsH[2][256 * 32];   // 32 KB  => 64 KB total

    const int tid = threadIdx.x;
    const int lane = tid & 63;
    const int w = tid >> 6;
    const int wm = w >> 1, wn = w & 1;
    const int mBase = blockIdx.y * 128, nBase = blockIdx.x * 256;
    Bh += (size_t)blockIdx.z * N * K;
    C  += (size_t)blockIdx.z * 512 * N;

    int aOff[2], ldsA[2], bOff[4], ldsB[4];
    #pragma unroll
    for (int p = 0; p < 2; ++p) {
        int c = w * 2 + p;
        int phys = c * 1024 + lane * 16;
        int lgc = phys ^ (((phys >> 7) & 3) << 4);
        aOff[p] = (mBase + (lgc >> 6)) * K + ((lgc & 63) >> 1);
        ldsA[p] = c * 512;
    }
    #pragma unroll
    for (int p = 0; p < 4; ++p) {
        int c = w * 4 + p;
        int phys = c * 1024 + lane * 16;
        int lgc = phys ^ (((phys >> 7) & 3) << 4);
        bOff[p] = (nBase + (lgc >> 6)) * K + ((lgc & 63) >> 1);
        ldsB[p] = c * 512;
    }

    const int kq = lane >> 4, rm = lane & 15;
    const int slot = kq ^ ((rm >> 1) & 3);

    v4f acc[4][8];
    #pragma unroll
    for (int i = 0; i < 4; ++i)
        #pragma unroll
        for (int j = 0; j < 8; ++j)
            acc[i][j] = (v4f){0.f, 0.f, 0.f, 0.f};

    auto stage = [&](int kt, int s) {
        const int ko = kt * 32;
        #pragma unroll
        for (int p = 0; p < 2; ++p) {
            GLL16(Ah + aOff[p] + ko, &AsH[s][ldsA[p]]);
            GLL16(Al + aOff[p] + ko, &AsL[s][ldsA[p]]);
        }
        #pragma unroll
        for (int p = 0; p < 4; ++p)
            GLL16(Bh + bOff[p] + ko, &BsH[s][ldsB[p]]);
    };
    stage(0, 0);
    stage(1, 1);      // 16 loads in flight

    for (int kt = 0; kt < KT; ++kt) {
        const int cs = kt & 1;
        if (kt < KT - 1) { WAIT_VM(8); } else { WAIT_VM(0); }
        SBAR(); SCHED();

        v8h ah[4], al[4], bh[8];
        #pragma unroll
        for (int i = 0; i < 4; ++i) {
            int rA = (wm * 64 + i * 16 + rm) * 32 + slot * 8;
            ah[i] = *(const v8h*)&AsH[cs][rA];
            al[i] = *(const v8h*)&AsL[cs][rA];
        }
        #pragma unroll
        for (int j = 0; j < 8; ++j) {
            int rB = (wn * 128 + j * 16 + rm) * 32 + slot * 8;
            bh[j] = *(const v8h*)&BsH[cs][rB];
        }
        WAIT_LGKM0(); SCHED();
        SBAR(); SCHED();

        if (kt + 2 < KT) stage(kt + 2, cs);

        #pragma unroll
        for (int i = 0; i < 4; ++i)
            #pragma unroll
            for (int j = 0; j < 8; ++j) {
                acc[i][j] = __builtin_amdgcn_mfma_f32_16x16x32_f16(
                    ah[i], bh[j], acc[i][j], 0, 0, 0);
                acc[i][j] = __builtin_amdgcn_mfma_f32_16x16x32_f16(
                    al[i], bh[j], acc[i][j], 0, 0, 0);
            }
        SCHED();
    }

    const int rq = lane >> 4, cn = lane & 15;
    #pragma unroll
    for (int i = 0; i < 4; ++i)
        #pragma unroll
        for (int rg = 0; rg < 4; ++rg) {
            int row = mBase + wm * 64 + i * 16 + rq * 4 + rg;
            float sc = bn_g[row] * rsqrtf(bn_v[row] + 1e-5f);
            float sh = bn_b[row] - bn_m[row] * sc;
            #pragma unroll
            for (int j = 0; j < 8; ++j) {
                int col = nBase + wn * 128 + j * 16 + cn;
                C[(size_t)row * N + col] = acc[i][j][rg] * sc + sh;
            }
        }
}

// ---------------------------------------------------------------------------
// fp32 -> (fp16 hi, fp16 lo) for BOTH weight tensors in one launch.
// ---------------------------------------------------------------------------
__global__ __launch_bounds__(256) void cvt_split2(
    const float* __restrict__ s1, f16* __restrict__ d1h, f16* __restrict__ d1l,
    int n4_1,
    const float* __restrict__ s2, f16* __restrict__ d2h, f16* __restrict__ d2l,
    int n4_2)
{
    int i = blockIdx.x * 256 + threadIdx.x;
    const float* src; f16* dh; f16* dl; int idx;
    if (i < n4_1) { src = s1; dh = d1h; dl = d1l; idx = i; }
    else if (i < n4_1 + n4_2) { src = s2; dh = d2h; dl = d2l; idx = i - n4_1; }
    else return;
    float4 f = ((const float4*)src)[idx];
    f16 h[4], l[4];
    float ff[4] = {f.x, f.y, f.z, f.w};
    #pragma unroll
    for (int q = 0; q < 4; ++q) {
        h[q] = (f16)ff[q];
        l[q] = (f16)(ff[q] - (float)h[q]);
    }
    *(uint2*)&dh[(size_t)idx * 4] = *(uint2*)h;
    *(uint2*)&dl[(size_t)idx * 4] = *(uint2*)l;
}

// ---------------------------------------------------------------------------
// Transpose + split: x (b, c=512, n=4096) fp32 -> x_t_h/l (b, n, c) fp16.
// ---------------------------------------------------------------------------
__global__ __launch_bounds__(256) void transp_split(
    const float* __restrict__ src, f16* __restrict__ dh, f16* __restrict__ dl)
{
    __shared__ float t[64][65];
    const int tid = threadIdx.x;
    const int n0 = blockIdx.x * 64, c0 = blockIdx.y * 64, b = blockIdx.z;

    const int row = tid >> 2;
    const int nn  = (tid & 3) * 16;
    const float* sp = src + ((size_t)b * 512 + c0 + row) * NPIX + n0 + nn;
    #pragma unroll
    for (int q = 0; q < 4; ++q) {
        float4 f = *(const float4*)(sp + q * 4);
        t[row][nn + q * 4 + 0] = f.x;
        t[row][nn + q * 4 + 1] = f.y;
        t[row][nn + q * 4 + 2] = f.z;
        t[row][nn + q * 4 + 3] = f.w;
    }
    __syncthreads();

    const int nrow = tid >> 2;
    const int cc   = (tid & 3) * 16;
    f16 h[16], l[16];
    #pragma unroll
    for (int q = 0; q < 16; ++q) {
        float f = t[cc + q][nrow];
        h[q] = (f16)f;
        l[q] = (f16)(f - (float)h[q]);
    }
    size_t di = ((size_t)b * NPIX + n0 + nrow) * 512 + c0 + cc;
    *(uint4*)&dh[di] = *(uint4*)&h[0];
    *(uint4*)&dh[di + 8] = *(uint4*)&h[8];
    *(uint4*)&dl[di] = *(uint4*)&l[0];
    *(uint4*)&dl[di + 8] = *(uint4*)&l[8];
}

// ---------------------------------------------------------------------------
// Fused depthwise 5x5 conv (pad 2) + per-group 8x8 mix. (v2, proven)
// ---------------------------------------------------------------------------
__global__ __launch_bounds__(256) void dwpw(
    const float* __restrict__ qkv, const float* __restrict__ w_dw,
    const float* __restrict__ w_pw, float* __restrict__ y)
{
    __shared__ float tile[8][36][68];   // 78336 B -> 2 blocks/CU

    const int tid = threadIdx.x;
    const int g = blockIdx.y;
    const int b = blockIdx.z;
    const int h0 = blockIdx.x * 32;
    const size_t cbase = (size_t)b * TD3 + g * 8;

    for (int idx = tid; idx < 288; idx += 256) {
        int ch = idx / 36, r = idx - ch * 36;
        *(float2*)&tile[ch][r][0]  = (float2){0.f, 0.f};
        *(float2*)&tile[ch][r][66] = (float2){0.f, 0.f};
    }
    #pragma unroll
    for (int it = 0; it < 18; ++it) {
        int idx = tid + it * 256;
        int ch = idx / 576;
        int rem = idx - ch * 576;
        int r = rem >> 4, q = rem & 15;
        int gh = h0 + r - 2;
        float4 v = {0.f, 0.f, 0.f, 0.f};
        if (gh >= 0 && gh < 64)
            v = *(const float4*)&qkv[(cbase + ch) * NPIX + gh * 64 + q * 4];
        *(float2*)&tile[ch][r][2 + q * 4] = (float2){v.x, v.y};
        *(float2*)&tile[ch][r][4 + q * 4] = (float2){v.z, v.w};
    }
    __syncthreads();

    const int wc0 = (tid & 15) * 4;
    const int rp  = tid >> 4;

    float acc[8][8];
    #pragma unroll
    for (int o = 0; o < 8; ++o)
        #pragma unroll
        for (int p = 0; p < 8; ++p) acc[o][p] = 0.f;

    #pragma unroll
    for (int ch = 0; ch < 8; ++ch) {
        const float* wdg = w_dw + (size_t)(g * 8 + ch) * 25;
        float wdr[25];
        #pragma unroll
        for (int t = 0; t < 25; ++t) wdr[t] = wdg[t];
        float wpr[8];
        #pragma unroll
        for (int o = 0; o < 8; ++o) wpr[o] = w_pw[g * 64 + o * 8 + ch];

        float w[6][8];
        #pragma unroll
        for (int rr = 0; rr < 6; ++rr) {
            *(float4*)&w[rr][0] = *(const float4*)&tile[ch][rp * 2 + rr][wc0];
            *(float4*)&w[rr][4] = *(const float4*)&tile[ch][rp * 2 + rr][wc0 + 4];
        }

        float dwv[8];
        #pragma unroll
        for (int s = 0; s < 2; ++s)
            #pragma unroll
            for (int cc = 0; cc < 4; ++cc) {
                float sum = 0.f;
                #pragma unroll
                for (int di = 0; di < 5; ++di)
                    #pragma unroll
                    for (int dj = 0; dj < 5; ++dj)
                        sum = fmaf(w[s + di][cc + dj], wdr[di * 5 + dj], sum);
                dwv[s * 4 + cc] = sum;
            }
        #pragma unroll
        for (int o = 0; o < 8; ++o)
            #pragma unroll
            for (int p = 0; p < 8; ++p)
                acc[o][p] = fmaf(dwv[p], wpr[o], acc[o][p]);
    }

    #pragma unroll
    for (int o = 0; o < 8; ++o)
        #pragma unroll
        for (int s = 0; s < 2; ++s) {
            float4 v = {acc[o][s * 4 + 0], acc[o][s * 4 + 1],
                        acc[o][s * 4 + 2], acc[o][s * 4 + 3]};
            *(float4*)&y[(cbase + o) * NPIX + (h0 + rp * 2 + s) * 64 + wc0] = v;
        }
}

// ---------------------------------------------------------------------------
// Attention stats per (b,h): vk[9][8] = sum_n [v;1][d,n] * relu(k)[e,n]
// ---------------------------------------------------------------------------
__global__ __launch_bounds__(256) void attn_stats(
    const float* __restrict__ qkv, const float* __restrict__ yy,
    float* __restrict__ vkout)
{
    const int h = blockIdx.x;
    const int b = blockIdx.y;
    const float* src = (h < 64)
        ? qkv + ((size_t)b * TD3 + h * 24) * NPIX
        : yy  + ((size_t)b * TD3 + (h - 64) * 24) * NPIX;

    float acc[9][8];
    #pragma unroll
    for (int d = 0; d < 9; ++d)
        #pragma unroll
        for (int e = 0; e < 8; ++e) acc[d][e] = 0.f;

    for (int n = threadIdx.x; n < NPIX; n += 256) {
        float kr[8], vv[8];
        #pragma unroll
        for (int e = 0; e < 8; ++e) kr[e] = fmaxf(src[(8 + e) * NPIX + n], 0.f);
        #pragma unroll
        for (int d = 0; d < 8; ++d) vv[d] = src[(16 + d) * NPIX + n];
        #pragma unroll
        for (int d = 0; d < 8; ++d)
            #pragma unroll
            for (int e = 0; e < 8; ++e) acc[d][e] = fmaf(vv[d], kr[e], acc[d][e]);
        #pragma unroll
        for (int e = 0; e < 8; ++e) acc[8][e] += kr[e];
    }

    __shared__ float part[4][72];
    const int lane = threadIdx.x & 63, wave = threadIdx.x >> 6;
    #pragma unroll
    for (int i = 0; i < 72; ++i) {
        float v = acc[i / 8][i % 8];
        #pragma unroll
        for (int off = 32; off; off >>= 1) v += __shfl_down(v, off, 64);
        if (lane == 0) part[wave][i] = v;
    }
    __syncthreads();
    if (threadIdx.x < 72) {
        float v = part[0][threadIdx.x] + part[1][threadIdx.x] +
                  part[2][threadIdx.x] + part[3][threadIdx.x];
        vkout[((size_t)b * 128 + h) * 72 + threadIdx.x] = v;
    }
}

// ---------------------------------------------------------------------------
// Attention apply -> fp16, written transposed: attout[(b*4096+n)*1024+h*8+d]
// ---------------------------------------------------------------------------
__global__ __launch_bounds__(256) void attn_apply_t(
    const float* __restrict__ qkv, const float* __restrict__ yy,
    const float* __restrict__ vkin, f16* __restrict__ attout)
{
    const int h = blockIdx.y;
    const int b = blockIdx.z;
    const int n = blockIdx.x * 256 + threadIdx.x;

    __shared__ float vk[72];
    if (threadIdx.x < 72)
        vk[threadIdx.x] = vkin[((size_t)b * 128 + h) * 72 + threadIdx.x];
    __syncthreads();

    const float* src = (h < 64)
        ? qkv + ((size_t)b * TD3 + h * 24) * NPIX
        : yy  + ((size_t)b * TD3 + (h - 64) * 24) * NPIX;

    float qr[8];
    #pragma unroll
    for (int e = 0; e < 8; ++e) qr[e] = fmaxf(src[e * NPIX + n], 0.f);

    float den = 0.f;
    #pragma unroll
    for (int e = 0; e < 8; ++e) den = fmaf(vk[64 + e], qr[e], den);
    float inv = 1.f / (den + 1e-15f);

    f16 o[8];
    #pragma unroll
    for (int d = 0; d < 8; ++d) {
        float num = 0.f;
        #pragma unroll
        for (int e = 0; e < 8; ++e) num = fmaf(vk[d * 8 + e], qr[e], num);
        o[d] = (f16)(num * inv);
    }
    *(uint4*)&attout[((size_t)b * NPIX + n) * 1024 + h * 8] = *(uint4*)o;
}

// ---------------------------------------------------------------------------
extern "C" void kernel_launch(void* const* d_in, const int* in_sizes, int n_in,
                              void* d_out, int out_size, void* d_ws, size_t ws_size,
                              hipStream_t stream)
{
    (void)in_sizes; (void)n_in; (void)out_size; (void)ws_size;
    const float* x      = (const float*)d_in[0];
    const float* w_qkv  = (const float*)d_in[1];
    const float* w_dw   = (const float*)d_in[2];
    const float* w_pw   = (const float*)d_in[3];
    const float* w_proj = (const float*)d_in[4];
    const float* bn_g   = (const float*)d_in[5];
    const float* bn_b   = (const float*)d_in[6];
    const float* bn_m   = (const float*)d_in[7];
    const float* bn_v   = (const float*)d_in[8];
    float* out = (float*)d_out;

    char* ws = (char*)d_ws;
    float* qkv     = (float*)(ws);
    float* y       = (float*)(ws + 100663296);
    f16*   x_t_h   = (f16*)(ws + 201326592);    // dead after qkv GEMM
    f16*   x_t_l   = (f16*)(ws + 218103808);    // dead after qkv GEMM
    f16*   attout  = (f16*)(ws + 201326592);    // overlays x_t_h/l
    f16*   w_qkv_h = (f16*)(ws + 234881024);
    f16*   w_qkv_l = (f16*)(ws + 236453888);
    f16*   w_proj_h= (f16*)(ws + 238026752);
    f16*   w_proj_l= (f16*)(ws + 239075328);
    float* vk      = out;                        // scratch; proj overwrites

    // 0. split both weight tensors to fp16 hi/lo (one launch)
    cvt_split2<<<1280, 256, 0, stream>>>(
        w_qkv, w_qkv_h, w_qkv_l, 196608,
        w_proj, w_proj_h, w_proj_l, 131072);
    // 1. x (b,c,n) -> x_t (b,n,c) fp16 hi/lo
    transp_split<<<dim3(64, 8, 4), 256, 0, stream>>>(x, x_t_h, x_t_l);
    // 2. qkv = w_qkv @ x  (M=1536,N=4096,K=512, batch 4), 3-pass split
    gemm_qkv<<<dim3(32, 8, 4), 256, 0, stream>>>(
        w_qkv_h, w_qkv_l, x_t_h, x_t_l, qkv);
    // 3. y = groupmix(dwconv5x5(qkv)), 32-row tiles
    dwpw<<<dim3(2, 192, 4), 256, 0, stream>>>(qkv, w_dw, w_pw, y);
    // 4. attention stats -> vk (in d_out)
    attn_stats<<<dim3(128, 4), 256, 0, stream>>>(qkv, y, vk);
    // 5. attention apply -> attout (b,n,c) fp16 (overwrites dead x_t region)
    attn_apply_t<<<dim3(16, 128, 4), 256, 0, stream>>>(qkv, y, vk, attout);
    // 6. out = BN(w_proj @ attout)  (M=512,N=4096,K=1024, batch 4), 2-pass
    gemm_proj<<<dim3(16, 4, 4), 256, 0, stream>>>(
        w_proj_h, w_proj_l, attout, out, bn_g, bn_b, bn_m, bn_v);
}

// Round 9
// 323.667 us; speedup vs baseline: 1.2683x; 1.0031x over previous
//
#include <hip/hip_runtime.h>
#include <cstddef>

// LiteMLA: qkv GEMM (split-fp16 MFMA, 3-pass) -> dwconv5x5+groupmix ->
// linear attention -> proj GEMM (split-A fp16 MFMA, 2-pass) + BN.
// B=4, C=512, H=W=64, N=4096, heads=128, 24 ch/head.
//
// Precision design: attention's relu(q)/relu(k) sign decisions amplify GEMM
// rounding (bf16 1-pass -> absmax 0.07). Split fp16 (hi+lo) gives ~2^-22
// rel GEMM error on qkv; proj is linear so split-A only suffices.
//
// GEMM v9 (post-mortem R8): qkv at 76us / MfmaUtil 45% / 1017 TF is at the
// LDS-issue local optimum of the 80KB 2-block counted-vmcnt structure (20
// b128 reads vs ~350cyc MFMA per wave-iter); left untouched. proj was the
// R6 trap: 256 blocks = 1 lockstep block/CU. v9 proj: 128x128 tile, ring-2
// = 48KB, grid 512 = 2 desynced blocks/CU, WAIT_VM(6) steady.
// Accumulation chain per C element unchanged -> bit-identical (absmax is
// the race detector: must stay 0.00390625).
//
// Workspace (peak 229 MiB): qkv fp32 @0; y fp32 @100663296; x_t_h/l fp16
// @201326592/@218103808 (dead after qkv GEMM); attout fp16 @201326592
// (overlays x_t); w_qkv_h/l @234881024; w_proj_h/l @238026752.
// vk stats (144 KB) live in d_out (proj GEMM fully overwrites d_out after).

#define NPIX 4096
#define TD3 1536

typedef _Float16 f16;
typedef __attribute__((ext_vector_type(8))) _Float16 v8h;
typedef __attribute__((ext_vector_type(4))) float v4f;

#define GLL16(g, l) __builtin_amdgcn_global_load_lds(                         \
    (const __attribute__((address_space(1))) unsigned int*)(g),               \
    (__attribute__((address_space(3))) unsigned int*)(l), 16, 0, 0)

#define WAIT_VM(n) asm volatile("s_waitcnt vmcnt(" #n ")" ::: "memory")
#define WAIT_LGKM0() asm volatile("s_waitcnt lgkmcnt(0)" ::: "memory")
#define SBAR() __builtin_amdgcn_s_barrier()
#define SCHED() __builtin_amdgcn_sched_barrier(0)

// ---------------------------------------------------------------------------
// qkv GEMM: C = Ah*Bh + Al*Bh + Ah*Bl. A=w_qkv (1536x512) hi/lo, B=x_t
// (4096x512) hi/lo, C (1536x4096) fp32, batched over z.
// 192x128 block, BK=32, 256 thr = 4 waves (2M x 2N), wave 96x64 (acc 6x4).
// Ring-2 XOR-swizzled LDS (80 KB) + counted vmcnt (10 GLL/thread/tile).
// Schedule/iter: WAIT_VM(10) -> barrier -> 20 ds_reads -> lgkmcnt(0) ->
// barrier -> stage(t+2) -> 72 MFMAs. vmcnt never 0 until the last iter.
// (R8-verified: 76us, MfmaUtil 45%, conflicts 0, absmax parity.)
// ---------------------------------------------------------------------------
__global__ __launch_bounds__(256, 2) void gemm_qkv(
    const f16* __restrict__ Ah, const f16* __restrict__ Al,
    const f16* __restrict__ Bh, const f16* __restrict__ Bl,
    float* __restrict__ C)
{
    const int N = 4096, K = 512, KT = 16;
    __shared__ f16 AsH[2][192 * 32];   // 24 KB
    __shared__ f16 AsL[2][192 * 32];   // 24 KB
    __shared__ f16 BsH[2][128 * 32];   // 16 KB
    __shared__ f16 BsL[2][128 * 32];   // 16 KB  => 80 KB total

    const int tid = threadIdx.x;
    const int lane = tid & 63;
    const int w = tid >> 6;
    const int wm = w >> 1, wn = w & 1;
    const int mBase = blockIdx.y * 192, nBase = blockIdx.x * 128;
    Bh += (size_t)blockIdx.z * N * K;
    Bl += (size_t)blockIdx.z * N * K;
    C  += (size_t)blockIdx.z * 1536 * N;

    // staging chunks (1 KB = 64 lanes x 16B). A: 12 chunks, wave w gets
    // w*3..w*3+2; B: 8 chunks, wave w gets w*2,w*2+1. GLOBAL source is
    // pre-swizzled (logical = phys ^ (((phys>>7)&3)<<4)) so the linear GLL
    // dest + swizzled ds_read agree (rule #21; verified R2/R3/R6/R8).
    int aOff[3], ldsA[3], bOff[2], ldsB[2];
    #pragma unroll
    for (int p = 0; p < 3; ++p) {
        int c = w * 3 + p;
        int phys = c * 1024 + lane * 16;
        int lgc = phys ^ (((phys >> 7) & 3) << 4);
        aOff[p] = (mBase + (lgc >> 6)) * K + ((lgc & 63) >> 1);
        ldsA[p] = c * 512;
    }
    #pragma unroll
    for (int p = 0; p < 2; ++p) {
        int c = w * 2 + p;
        int phys = c * 1024 + lane * 16;
        int lgc = phys ^ (((phys >> 7) & 3) << 4);
        bOff[p] = (nBase + (lgc >> 6)) * K + ((lgc & 63) >> 1);
        ldsB[p] = c * 512;
    }

    const int kq = lane >> 4, rm = lane & 15;
    const int slot = kq ^ ((rm >> 1) & 3);   // conflict-free read slot

    v4f acc[6][4];
    #pragma unroll
    for (int i = 0; i < 6; ++i)
        #pragma unroll
        for (int j = 0; j < 4; ++j)
            acc[i][j] = (v4f){0.f, 0.f, 0.f, 0.f};

    auto stage = [&](int kt, int s) {
        const int ko = kt * 32;
        #pragma unroll
        for (int p = 0; p < 3; ++p) {
            GLL16(Ah + aOff[p] + ko, &AsH[s][ldsA[p]]);
            GLL16(Al + aOff[p] + ko, &AsL[s][ldsA[p]]);
        }
        #pragma unroll
        for (int p = 0; p < 2; ++p) {
            GLL16(Bh + bOff[p] + ko, &BsH[s][ldsB[p]]);
            GLL16(Bl + bOff[p] + ko, &BsL[s][ldsB[p]]);
        }
    };
    stage(0, 0);
    stage(1, 1);      // 20 loads in flight

    for (int kt = 0; kt < KT; ++kt) {
        const int cs = kt & 1;
        // tile t landed; tile t+1's 10 loads stay IN FLIGHT (per-wave,
        // in-order retirement; each wave counts only its own loads)
        if (kt < KT - 1) { WAIT_VM(10); } else { WAIT_VM(0); }
        SBAR(); SCHED();

        v8h ah[6], al[6], bh[4], bl[4];
        #pragma unroll
        for (int i = 0; i < 6; ++i) {
            int rA = (wm * 96 + i * 16 + rm) * 32 + slot * 8;
            ah[i] = *(const v8h*)&AsH[cs][rA];
            al[i] = *(const v8h*)&AsL[cs][rA];
        }
        #pragma unroll
        for (int j = 0; j < 4; ++j) {
            int rB = (wn * 64 + j * 16 + rm) * 32 + slot * 8;
            bh[j] = *(const v8h*)&BsH[cs][rB];
            bl[j] = *(const v8h*)&BsL[cs][rB];
        }
        WAIT_LGKM0(); SCHED();
        SBAR(); SCHED();          // all waves' reads of slot cs complete

        if (kt + 2 < KT) stage(kt + 2, cs);   // overwrite cs; lands >=300cyc
                                              // later, under the MFMAs below
        #pragma unroll
        for (int i = 0; i < 6; ++i)
            #pragma unroll
            for (int j = 0; j < 4; ++j) {
                acc[i][j] = __builtin_amdgcn_mfma_f32_16x16x32_f16(
                    ah[i], bh[j], acc[i][j], 0, 0, 0);
                acc[i][j] = __builtin_amdgcn_mfma_f32_16x16x32_f16(
                    al[i], bh[j], acc[i][j], 0, 0, 0);
                acc[i][j] = __builtin_amdgcn_mfma_f32_16x16x32_f16(
                    ah[i], bl[j], acc[i][j], 0, 0, 0);
            }
        SCHED();
    }

    // epilogue: D row=(lane>>4)*4+reg, col=lane&15
    const int rq = lane >> 4, cn = lane & 15;
    #pragma unroll
    for (int i = 0; i < 6; ++i)
        #pragma unroll
        for (int rg = 0; rg < 4; ++rg) {
            int row = mBase + wm * 96 + i * 16 + rq * 4 + rg;
            #pragma unroll
            for (int j = 0; j < 4; ++j) {
                int col = nBase + wn * 64 + j * 16 + cn;
                C[(size_t)row * N + col] = acc[i][j][rg];
            }
        }
}

// ---------------------------------------------------------------------------
// proj GEMM + BN: C = BN(Ah*Bh + Al*Bh). A=w_proj (512x1024) hi/lo,
// B=attout (4096x1024) fp16, C (512x4096) fp32, batched over z.
// v9: 128x128 block, BK=32, 256 thr = 4 waves (2M x 2N), wave 64x64
// (acc 4x4). Ring-2 LDS = 48 KB -> 2 desynced blocks/CU (R3-vs-R6 lesson:
// the lockstep 1-block/CU config loses ~30%). 6 GLL/thread/tile ->
// WAIT_VM(6) steady, never drains. Grid 32x4x4 = 512 blocks = 2/CU.
// ---------------------------------------------------------------------------
__global__ __launch_bounds__(256, 2) void gemm_proj(
    const f16* __restrict__ Ah, const f16* __restrict__ Al,
    const f16* __restrict__ Bh, float* __restrict__ C,
    const float* __restrict__ bn_g, const float* __restrict__ bn_b,
    const float* __restrict__ bn_m, const float* __restrict__ bn_v)
{
    const int N = 4096, K = 1024, KT = 32;
    __shared__ f16 AsH[2][128 * 32];   // 16 KB
    __shared__ f16 AsL[2][128 * 32];   // 16 KB
    __shared__ f16 BsH[2][128 * 32];   // 16 KB  => 48 KB total

    const int tid = threadIdx.x;
    const int lane = tid & 63;
    const int w = tid >> 6;
    const int wm = w >> 1, wn = w & 1;
    const int mBase = blockIdx.y * 128, nBase = blockIdx.x * 128;
    Bh += (size_t)blockIdx.z * N * K;
    C  += (size_t)blockIdx.z * 512 * N;

    // 8 chunks per 8KB tile; wave w does chunks w*2, w*2+1 (A and B).
    int aOff[2], ldsA[2], bOff[2], ldsB[2];
    #pragma unroll
    for (int p = 0; p < 2; ++p) {
        int c = w * 2 + p;
        int phys = c * 1024 + lane * 16;
        int lgc = phys ^ (((phys >> 7) & 3) << 4);
        aOff[p] = (mBase + (lgc >> 6)) * K + ((lgc & 63) >> 1);
        bOff[p] = (nBase + (lgc >> 6)) * K + ((lgc & 63) >> 1);
        ldsA[p] = c * 512;
        ldsB[p] = c * 512;
    }

    const int kq = lane >> 4, rm = lane & 15;
    const int slot = kq ^ ((rm >> 1) & 3);

    v4f acc[4][4];
    #pragma unroll
    for (int i = 0; i < 4; ++i)
        #pragma unroll
        for (int j = 0; j < 4; ++j)
            acc[i][j] = (v4f){0.f, 0.f, 0.f, 0.f};

    auto stage = [&](int kt, int s) {
        const int ko = kt * 32;
        #pragma unroll
        for (int p = 0; p < 2; ++p) {
            GLL16(Ah + aOff[p] + ko, &AsH[s][ldsA[p]]);
            GLL16(Al + aOff[p] + ko, &AsL[s][ldsA[p]]);
            GLL16(Bh + bOff[p] + ko, &BsH[s][ldsB[p]]);
        }
    };
    stage(0, 0);
    stage(1, 1);      // 12 loads in flight

    for (int kt = 0; kt < KT; ++kt) {
        const int cs = kt & 1;
        if (kt < KT - 1) { WAIT_VM(6); } else { WAIT_VM(0); }
        SBAR(); SCHED();

        v8h ah[4], al[4], bh[4];
        #pragma unroll
        for (int i = 0; i < 4; ++i) {
            int rA = (wm * 64 + i * 16 + rm) * 32 + slot * 8;
            ah[i] = *(const v8h*)&AsH[cs][rA];
            al[i] = *(const v8h*)&AsL[cs][rA];
        }
        #pragma unroll
        for (int j = 0; j < 4; ++j) {
            int rB = (wn * 64 + j * 16 + rm) * 32 + slot * 8;
            bh[j] = *(const v8h*)&BsH[cs][rB];
        }
        WAIT_LGKM0(); SCHED();
        SBAR(); SCHED();

        if (kt + 2 < KT) stage(kt + 2, cs);

        #pragma unroll
        for (int i = 0; i < 4; ++i)
            #pragma unroll
            for (int j = 0; j < 4; ++j) {
                acc[i][j] = __builtin_amdgcn_mfma_f32_16x16x32_f16(
                    ah[i], bh[j], acc[i][j], 0, 0, 0);
                acc[i][j] = __builtin_amdgcn_mfma_f32_16x16x32_f16(
                    al[i], bh[j], acc[i][j], 0, 0, 0);
            }
        SCHED();
    }

    const int rq = lane >> 4, cn = lane & 15;
    #pragma unroll
    for (int i = 0; i < 4; ++i)
        #pragma unroll
        for (int rg = 0; rg < 4; ++rg) {
            int row = mBase + wm * 64 + i * 16 + rq * 4 + rg;
            float sc = bn_g[row] * rsqrtf(bn_v[row] + 1e-5f);
            float sh = bn_b[row] - bn_m[row] * sc;
            #pragma unroll
            for (int j = 0; j < 4; ++j) {
                int col = nBase + wn * 64 + j * 16 + cn;
                C[(size_t)row * N + col] = acc[i][j][rg] * sc + sh;
            }
        }
}

// ---------------------------------------------------------------------------
// fp32 -> (fp16 hi, fp16 lo) for BOTH weight tensors in one launch.
// ---------------------------------------------------------------------------
__global__ __launch_bounds__(256) void cvt_split2(
    const float* __restrict__ s1, f16* __restrict__ d1h, f16* __restrict__ d1l,
    int n4_1,
    const float* __restrict__ s2, f16* __restrict__ d2h, f16* __restrict__ d2l,
    int n4_2)
{
    int i = blockIdx.x * 256 + threadIdx.x;
    const float* src; f16* dh; f16* dl; int idx;
    if (i < n4_1) { src = s1; dh = d1h; dl = d1l; idx = i; }
    else if (i < n4_1 + n4_2) { src = s2; dh = d2h; dl = d2l; idx = i - n4_1; }
    else return;
    float4 f = ((const float4*)src)[idx];
    f16 h[4], l[4];
    float ff[4] = {f.x, f.y, f.z, f.w};
    #pragma unroll
    for (int q = 0; q < 4; ++q) {
        h[q] = (f16)ff[q];
        l[q] = (f16)(ff[q] - (float)h[q]);
    }
    *(uint2*)&dh[(size_t)idx * 4] = *(uint2*)h;
    *(uint2*)&dl[(size_t)idx * 4] = *(uint2*)l;
}

// ---------------------------------------------------------------------------
// Transpose + split: x (b, c=512, n=4096) fp32 -> x_t_h/l (b, n, c) fp16.
// ---------------------------------------------------------------------------
__global__ __launch_bounds__(256) void transp_split(
    const float* __restrict__ src, f16* __restrict__ dh, f16* __restrict__ dl)
{
    __shared__ float t[64][65];
    const int tid = threadIdx.x;
    const int n0 = blockIdx.x * 64, c0 = blockIdx.y * 64, b = blockIdx.z;

    const int row = tid >> 2;
    const int nn  = (tid & 3) * 16;
    const float* sp = src + ((size_t)b * 512 + c0 + row) * NPIX + n0 + nn;
    #pragma unroll
    for (int q = 0; q < 4; ++q) {
        float4 f = *(const float4*)(sp + q * 4);
        t[row][nn + q * 4 + 0] = f.x;
        t[row][nn + q * 4 + 1] = f.y;
        t[row][nn + q * 4 + 2] = f.z;
        t[row][nn + q * 4 + 3] = f.w;
    }
    __syncthreads();

    const int nrow = tid >> 2;
    const int cc   = (tid & 3) * 16;
    f16 h[16], l[16];
    #pragma unroll
    for (int q = 0; q < 16; ++q) {
        float f = t[cc + q][nrow];
        h[q] = (f16)f;
        l[q] = (f16)(f - (float)h[q]);
    }
    size_t di = ((size_t)b * NPIX + n0 + nrow) * 512 + c0 + cc;
    *(uint4*)&dh[di] = *(uint4*)&h[0];
    *(uint4*)&dh[di + 8] = *(uint4*)&h[8];
    *(uint4*)&dl[di] = *(uint4*)&l[0];
    *(uint4*)&dl[di + 8] = *(uint4*)&l[8];
}

// ---------------------------------------------------------------------------
// Fused depthwise 5x5 conv (pad 2) + per-group 8x8 mix. (v2, proven)
// ---------------------------------------------------------------------------
__global__ __launch_bounds__(256) void dwpw(
    const float* __restrict__ qkv, const float* __restrict__ w_dw,
    const float* __restrict__ w_pw, float* __restrict__ y)
{
    __shared__ float tile[8][36][68];   // 78336 B -> 2 blocks/CU

    const int tid = threadIdx.x;
    const int g = blockIdx.y;
    const int b = blockIdx.z;
    const int h0 = blockIdx.x * 32;
    const size_t cbase = (size_t)b * TD3 + g * 8;

    for (int idx = tid; idx < 288; idx += 256) {
        int ch = idx / 36, r = idx - ch * 36;
        *(float2*)&tile[ch][r][0]  = (float2){0.f, 0.f};
        *(float2*)&tile[ch][r][66] = (float2){0.f, 0.f};
    }
    #pragma unroll
    for (int it = 0; it < 18; ++it) {
        int idx = tid + it * 256;
        int ch = idx / 576;
        int rem = idx - ch * 576;
        int r = rem >> 4, q = rem & 15;
        int gh = h0 + r - 2;
        float4 v = {0.f, 0.f, 0.f, 0.f};
        if (gh >= 0 && gh < 64)
            v = *(const float4*)&qkv[(cbase + ch) * NPIX + gh * 64 + q * 4];
        *(float2*)&tile[ch][r][2 + q * 4] = (float2){v.x, v.y};
        *(float2*)&tile[ch][r][4 + q * 4] = (float2){v.z, v.w};
    }
    __syncthreads();

    const int wc0 = (tid & 15) * 4;
    const int rp  = tid >> 4;

    float acc[8][8];
    #pragma unroll
    for (int o = 0; o < 8; ++o)
        #pragma unroll
        for (int p = 0; p < 8; ++p) acc[o][p] = 0.f;

    #pragma unroll
    for (int ch = 0; ch < 8; ++ch) {
        const float* wdg = w_dw + (size_t)(g * 8 + ch) * 25;
        float wdr[25];
        #pragma unroll
        for (int t = 0; t < 25; ++t) wdr[t] = wdg[t];
        float wpr[8];
        #pragma unroll
        for (int o = 0; o < 8; ++o) wpr[o] = w_pw[g * 64 + o * 8 + ch];

        float w[6][8];
        #pragma unroll
        for (int rr = 0; rr < 6; ++rr) {
            *(float4*)&w[rr][0] = *(const float4*)&tile[ch][rp * 2 + rr][wc0];
            *(float4*)&w[rr][4] = *(const float4*)&tile[ch][rp * 2 + rr][wc0 + 4];
        }

        float dwv[8];
        #pragma unroll
        for (int s = 0; s < 2; ++s)
            #pragma unroll
            for (int cc = 0; cc < 4; ++cc) {
                float sum = 0.f;
                #pragma unroll
                for (int di = 0; di < 5; ++di)
                    #pragma unroll
                    for (int dj = 0; dj < 5; ++dj)
                        sum = fmaf(w[s + di][cc + dj], wdr[di * 5 + dj], sum);
                dwv[s * 4 + cc] = sum;
            }
        #pragma unroll
        for (int o = 0; o < 8; ++o)
            #pragma unroll
            for (int p = 0; p < 8; ++p)
                acc[o][p] = fmaf(dwv[p], wpr[o], acc[o][p]);
    }

    #pragma unroll
    for (int o = 0; o < 8; ++o)
        #pragma unroll
        for (int s = 0; s < 2; ++s) {
            float4 v = {acc[o][s * 4 + 0], acc[o][s * 4 + 1],
                        acc[o][s * 4 + 2], acc[o][s * 4 + 3]};
            *(float4*)&y[(cbase + o) * NPIX + (h0 + rp * 2 + s) * 64 + wc0] = v;
        }
}

// ---------------------------------------------------------------------------
// Attention stats per (b,h): vk[9][8] = sum_n [v;1][d,n] * relu(k)[e,n]
// ---------------------------------------------------------------------------
__global__ __launch_bounds__(256) void attn_stats(
    const float* __restrict__ qkv, const float* __restrict__ yy,
    float* __restrict__ vkout)
{
    const int h = blockIdx.x;
    const int b = blockIdx.y;
    const float* src = (h < 64)
        ? qkv + ((size_t)b * TD3 + h * 24) * NPIX
        : yy  + ((size_t)b * TD3 + (h - 64) * 24) * NPIX;

    float acc[9][8];
    #pragma unroll
    for (int d = 0; d < 9; ++d)
        #pragma unroll
        for (int e = 0; e < 8; ++e) acc[d][e] = 0.f;

    for (int n = threadIdx.x; n < NPIX; n += 256) {
        float kr[8], vv[8];
        #pragma unroll
        for (int e = 0; e < 8; ++e) kr[e] = fmaxf(src[(8 + e) * NPIX + n], 0.f);
        #pragma unroll
        for (int d = 0; d < 8; ++d) vv[d] = src[(16 + d) * NPIX + n];
        #pragma unroll
        for (int d = 0; d < 8; ++d)
            #pragma unroll
            for (int e = 0; e < 8; ++e) acc[d][e] = fmaf(vv[d], kr[e], acc[d][e]);
        #pragma unroll
        for (int e = 0; e < 8; ++e) acc[8][e] += kr[e];
    }

    __shared__ float part[4][72];
    const int lane = threadIdx.x & 63, wave = threadIdx.x >> 6;
    #pragma unroll
    for (int i = 0; i < 72; ++i) {
        float v = acc[i / 8][i % 8];
        #pragma unroll
        for (int off = 32; off; off >>= 1) v += __shfl_down(v, off, 64);
        if (lane == 0) part[wave][i] = v;
    }
    __syncthreads();
    if (threadIdx.x < 72) {
        float v = part[0][threadIdx.x] + part[1][threadIdx.x] +
                  part[2][threadIdx.x] + part[3][threadIdx.x];
        vkout[((size_t)b * 128 + h) * 72 + threadIdx.x] = v;
    }
}

// ---------------------------------------------------------------------------
// Attention apply -> fp16, written transposed: attout[(b*4096+n)*1024+h*8+d]
// ---------------------------------------------------------------------------
__global__ __launch_bounds__(256) void attn_apply_t(
    const float* __restrict__ qkv, const float* __restrict__ yy,
    const float* __restrict__ vkin, f16* __restrict__ attout)
{
    const int h = blockIdx.y;
    const int b = blockIdx.z;
    const int n = blockIdx.x * 256 + threadIdx.x;

    __shared__ float vk[72];
    if (threadIdx.x < 72)
        vk[threadIdx.x] = vkin[((size_t)b * 128 + h) * 72 + threadIdx.x];
    __syncthreads();

    const float* src = (h < 64)
        ? qkv + ((size_t)b * TD3 + h * 24) * NPIX
        : yy  + ((size_t)b * TD3 + (h - 64) * 24) * NPIX;

    float qr[8];
    #pragma unroll
    for (int e = 0; e < 8; ++e) qr[e] = fmaxf(src[e * NPIX + n], 0.f);

    float den = 0.f;
    #pragma unroll
    for (int e = 0; e < 8; ++e) den = fmaf(vk[64 + e], qr[e], den);
    float inv = 1.f / (den + 1e-15f);

    f16 o[8];
    #pragma unroll
    for (int d = 0; d < 8; ++d) {
        float num = 0.f;
        #pragma unroll
        for (int e = 0; e < 8; ++e) num = fmaf(vk[d * 8 + e], qr[e], num);
        o[d] = (f16)(num * inv);
    }
    *(uint4*)&attout[((size_t)b * NPIX + n) * 1024 + h * 8] = *(uint4*)o;
}

// ---------------------------------------------------------------------------
extern "C" void kernel_launch(void* const* d_in, const int* in_sizes, int n_in,
                              void* d_out, int out_size, void* d_ws, size_t ws_size,
                              hipStream_t stream)
{
    (void)in_sizes; (void)n_in; (void)out_size; (void)ws_size;
    const float* x      = (const float*)d_in[0];
    const float* w_qkv  = (const float*)d_in[1];
    const float* w_dw   = (const float*)d_in[2];
    const float* w_pw   = (const float*)d_in[3];
    const float* w_proj = (const float*)d_in[4];
    const float* bn_g   = (const float*)d_in[5];
    const float* bn_b   = (const float*)d_in[6];
    const float* bn_m   = (const float*)d_in[7];
    const float* bn_v   = (const float*)d_in[8];
    float* out = (float*)d_out;

    char* ws = (char*)d_ws;
    float* qkv     = (float*)(ws);
    float* y       = (float*)(ws + 100663296);
    f16*   x_t_h   = (f16*)(ws + 201326592);    // dead after qkv GEMM
    f16*   x_t_l   = (f16*)(ws + 218103808);    // dead after qkv GEMM
    f16*   attout  = (f16*)(ws + 201326592);    // overlays x_t_h/l
    f16*   w_qkv_h = (f16*)(ws + 234881024);
    f16*   w_qkv_l = (f16*)(ws + 236453888);
    f16*   w_proj_h= (f16*)(ws + 238026752);
    f16*   w_proj_l= (f16*)(ws + 239075328);
    float* vk      = out;                        // scratch; proj overwrites

    // 0. split both weight tensors to fp16 hi/lo (one launch)
    cvt_split2<<<1280, 256, 0, stream>>>(
        w_qkv, w_qkv_h, w_qkv_l, 196608,
        w_proj, w_proj_h, w_proj_l, 131072);
    // 1. x (b,c,n) -> x_t (b,n,c) fp16 hi/lo
    transp_split<<<dim3(64, 8, 4), 256, 0, stream>>>(x, x_t_h, x_t_l);
    // 2. qkv = w_qkv @ x  (M=1536,N=4096,K=512, batch 4), 3-pass split
    gemm_qkv<<<dim3(32, 8, 4), 256, 0, stream>>>(
        w_qkv_h, w_qkv_l, x_t_h, x_t_l, qkv);
    // 3. y = groupmix(dwconv5x5(qkv)), 32-row tiles
    dwpw<<<dim3(2, 192, 4), 256, 0, stream>>>(qkv, w_dw, w_pw, y);
    // 4. attention stats -> vk (in d_out)
    attn_stats<<<dim3(128, 4), 256, 0, stream>>>(qkv, y, vk);
    // 5. attention apply -> attout (b,n,c) fp16 (overwrites dead x_t region)
    attn_apply_t<<<dim3(16, 128, 4), 256, 0, stream>>>(qkv, y, vk, attout);
    // 6. out = BN(w_proj @ attout)  (M=512,N=4096,K=1024, batch 4), 2-pass
    //    128x128 tile, 512 blocks = 2 desynced blocks/CU
    gemm_proj<<<dim3(32, 4, 4), 256, 0, stream>>>(
        w_proj_h, w_proj_l, attout, out, bn_g, bn_b, bn_m, bn_v);
}

// Round 10
// 322.276 us; speedup vs baseline: 1.2737x; 1.0043x over previous
//
#include <hip/hip_runtime.h>
#include <cstddef>

// LiteMLA: qkv GEMM (split-fp16 MFMA, 3-pass) -> dwconv5x5+groupmix ->
// linear attention -> proj GEMM (split-A fp16 MFMA, 2-pass) + BN.
// B=4, C=512, H=W=64, N=4096, heads=128, 24 ch/head.
//
// Precision design: attention's relu(q)/relu(k) sign decisions amplify GEMM
// rounding (bf16 1-pass -> absmax 0.07). Split fp16 (hi+lo) gives ~2^-22
// rel GEMM error on qkv; proj is linear so split-A only suffices.
//
// GEMM v10 (post-mortem R9): R8/R9's iter structure pinned
// reads -> lgkmcnt(0) -> sched_barrier -> MFMAs, defeating the compiler's
// fine-grained lgkmcnt interleave (m97/m141 lesson) -> each wave drained
// ALL 20 ds_reads before ANY MFMA; MfmaUtil stuck at 44% vs the 37us
// per-CU matrix-pipe floor. v10 makes reads+MFMAs ONE compiler-scheduled
// region and moves the ring-safety drain (lgkmcnt(0)+barrier+stage) to the
// iteration TAIL. vmcnt accounting unchanged (stage at tail => WAIT_VM(L)
// at head still = "tile t landed, t+1 in flight"). MFMA order per acc
// element unchanged -> bit-identical (absmax 0.00390625 = race detector).
//
// Workspace (peak 229 MiB): qkv fp32 @0; y fp32 @100663296; x_t_h/l fp16
// @201326592/@218103808 (dead after qkv GEMM); attout fp16 @201326592
// (overlays x_t); w_qkv_h/l @234881024; w_proj_h/l @238026752.
// vk stats (144 KB) live in d_out (proj GEMM fully overwrites d_out after).

#define NPIX 4096
#define TD3 1536

typedef _Float16 f16;
typedef __attribute__((ext_vector_type(8))) _Float16 v8h;
typedef __attribute__((ext_vector_type(4))) float v4f;

#define GLL16(g, l) __builtin_amdgcn_global_load_lds(                         \
    (const __attribute__((address_space(1))) unsigned int*)(g),               \
    (__attribute__((address_space(3))) unsigned int*)(l), 16, 0, 0)

#define WAIT_VM(n) asm volatile("s_waitcnt vmcnt(" #n ")" ::: "memory")
#define WAIT_LGKM0() asm volatile("s_waitcnt lgkmcnt(0)" ::: "memory")
#define SBAR() __builtin_amdgcn_s_barrier()
#define SCHED() __builtin_amdgcn_sched_barrier(0)

// ---------------------------------------------------------------------------
// qkv GEMM: C = Ah*Bh + Al*Bh + Ah*Bl. A=w_qkv (1536x512) hi/lo, B=x_t
// (4096x512) hi/lo, C (1536x4096) fp32, batched over z.
// 192x128 block, BK=32, 256 thr = 4 waves (2M x 2N), wave 96x64 (acc 6x4).
// Ring-2 XOR-swizzled LDS (80 KB, 2 blocks/CU) + counted vmcnt
// (10 GLL/thread/tile). Per iter: WAIT_VM(10) -> barrier ->
// {20 ds_reads + 72 MFMAs, compiler-interleaved} -> lgkmcnt(0) -> barrier
// -> stage(t+2). vmcnt never 0 until the last iter.
// ---------------------------------------------------------------------------
__global__ __launch_bounds__(256, 2) void gemm_qkv(
    const f16* __restrict__ Ah, const f16* __restrict__ Al,
    const f16* __restrict__ Bh, const f16* __restrict__ Bl,
    float* __restrict__ C)
{
    const int N = 4096, K = 512, KT = 16;
    __shared__ f16 AsH[2][192 * 32];   // 24 KB
    __shared__ f16 AsL[2][192 * 32];   // 24 KB
    __shared__ f16 BsH[2][128 * 32];   // 16 KB
    __shared__ f16 BsL[2][128 * 32];   // 16 KB  => 80 KB total

    const int tid = threadIdx.x;
    const int lane = tid & 63;
    const int w = tid >> 6;
    const int wm = w >> 1, wn = w & 1;
    const int mBase = blockIdx.y * 192, nBase = blockIdx.x * 128;
    Bh += (size_t)blockIdx.z * N * K;
    Bl += (size_t)blockIdx.z * N * K;
    C  += (size_t)blockIdx.z * 1536 * N;

    // staging chunks (1 KB = 64 lanes x 16B). A: 12 chunks, wave w gets
    // w*3..w*3+2; B: 8 chunks, wave w gets w*2,w*2+1. GLOBAL source is
    // pre-swizzled (logical = phys ^ (((phys>>7)&3)<<4)) so the linear GLL
    // dest + swizzled ds_read agree (rule #21; verified R2/R3/R6/R8).
    int aOff[3], ldsA[3], bOff[2], ldsB[2];
    #pragma unroll
    for (int p = 0; p < 3; ++p) {
        int c = w * 3 + p;
        int phys = c * 1024 + lane * 16;
        int lgc = phys ^ (((phys >> 7) & 3) << 4);
        aOff[p] = (mBase + (lgc >> 6)) * K + ((lgc & 63) >> 1);
        ldsA[p] = c * 512;
    }
    #pragma unroll
    for (int p = 0; p < 2; ++p) {
        int c = w * 2 + p;
        int phys = c * 1024 + lane * 16;
        int lgc = phys ^ (((phys >> 7) & 3) << 4);
        bOff[p] = (nBase + (lgc >> 6)) * K + ((lgc & 63) >> 1);
        ldsB[p] = c * 512;
    }

    const int kq = lane >> 4, rm = lane & 15;
    const int slot = kq ^ ((rm >> 1) & 3);   // conflict-free read slot

    v4f acc[6][4];
    #pragma unroll
    for (int i = 0; i < 6; ++i)
        #pragma unroll
        for (int j = 0; j < 4; ++j)
            acc[i][j] = (v4f){0.f, 0.f, 0.f, 0.f};

    auto stage = [&](int kt, int s) {
        const int ko = kt * 32;
        #pragma unroll
        for (int p = 0; p < 3; ++p) {
            GLL16(Ah + aOff[p] + ko, &AsH[s][ldsA[p]]);
            GLL16(Al + aOff[p] + ko, &AsL[s][ldsA[p]]);
        }
        #pragma unroll
        for (int p = 0; p < 2; ++p) {
            GLL16(Bh + bOff[p] + ko, &BsH[s][ldsB[p]]);
            GLL16(Bl + bOff[p] + ko, &BsL[s][ldsB[p]]);
        }
    };
    stage(0, 0);
    stage(1, 1);      // 20 loads in flight

    for (int kt = 0; kt < KT; ++kt) {
        const int cs = kt & 1;
        // tile t landed; tile t+1's 10 loads stay IN FLIGHT (per-wave,
        // in-order retirement; each wave counts only its own loads)
        if (kt < KT - 1) { WAIT_VM(10); } else { WAIT_VM(0); }
        SBAR(); SCHED();

        // reads + MFMAs: ONE compiler-scheduled region. The compiler emits
        // fine-grained lgkmcnt(N) so early MFMAs overlap late ds_reads.
        v8h ah[6], al[6], bh[4], bl[4];
        #pragma unroll
        for (int i = 0; i < 6; ++i) {
            int rA = (wm * 96 + i * 16 + rm) * 32 + slot * 8;
            ah[i] = *(const v8h*)&AsH[cs][rA];
            al[i] = *(const v8h*)&AsL[cs][rA];
        }
        #pragma unroll
        for (int j = 0; j < 4; ++j) {
            int rB = (wn * 64 + j * 16 + rm) * 32 + slot * 8;
            bh[j] = *(const v8h*)&BsH[cs][rB];
            bl[j] = *(const v8h*)&BsL[cs][rB];
        }
        #pragma unroll
        for (int i = 0; i < 6; ++i)
            #pragma unroll
            for (int j = 0; j < 4; ++j) {
                acc[i][j] = __builtin_amdgcn_mfma_f32_16x16x32_f16(
                    ah[i], bh[j], acc[i][j], 0, 0, 0);
                acc[i][j] = __builtin_amdgcn_mfma_f32_16x16x32_f16(
                    al[i], bh[j], acc[i][j], 0, 0, 0);
                acc[i][j] = __builtin_amdgcn_mfma_f32_16x16x32_f16(
                    ah[i], bl[j], acc[i][j], 0, 0, 0);
            }

        // ring safety: all waves' reads of slot cs complete before the
        // overwrite below. lgkmcnt(0) is ~free (reads already consumed).
        WAIT_LGKM0();
        SBAR(); SCHED();
        if (kt + 2 < KT) stage(kt + 2, cs);   // lands during next iter
    }

    // epilogue: D row=(lane>>4)*4+reg, col=lane&15
    const int rq = lane >> 4, cn = lane & 15;
    #pragma unroll
    for (int i = 0; i < 6; ++i)
        #pragma unroll
        for (int rg = 0; rg < 4; ++rg) {
            int row = mBase + wm * 96 + i * 16 + rq * 4 + rg;
            #pragma unroll
            for (int j = 0; j < 4; ++j) {
                int col = nBase + wn * 64 + j * 16 + cn;
                C[(size_t)row * N + col] = acc[i][j][rg];
            }
        }
}

// ---------------------------------------------------------------------------
// proj GEMM + BN: C = BN(Ah*Bh + Al*Bh). A=w_proj (512x1024) hi/lo,
// B=attout (4096x1024) fp16, C (512x4096) fp32, batched over z.
// 128x128 block, BK=32, 256 thr = 4 waves (2M x 2N), wave 64x64 (acc 4x4).
// Ring-2 LDS = 48 KB -> 2 desynced blocks/CU; WAIT_VM(6) steady.
// Same v10 un-pinned read+MFMA region as gemm_qkv.
// ---------------------------------------------------------------------------
__global__ __launch_bounds__(256, 2) void gemm_proj(
    const f16* __restrict__ Ah, const f16* __restrict__ Al,
    const f16* __restrict__ Bh, float* __restrict__ C,
    const float* __restrict__ bn_g, const float* __restrict__ bn_b,
    const float* __restrict__ bn_m, const float* __restrict__ bn_v)
{
    const int N = 4096, K = 1024, KT = 32;
    __shared__ f16 AsH[2][128 * 32];   // 16 KB
    __shared__ f16 AsL[2][128 * 32];   // 16 KB
    __shared__ f16 BsH[2][128 * 32];   // 16 KB  => 48 KB total

    const int tid = threadIdx.x;
    const int lane = tid & 63;
    const int w = tid >> 6;
    const int wm = w >> 1, wn = w & 1;
    const int mBase = blockIdx.y * 128, nBase = blockIdx.x * 128;
    Bh += (size_t)blockIdx.z * N * K;
    C  += (size_t)blockIdx.z * 512 * N;

    // 8 chunks per 8KB tile; wave w does chunks w*2, w*2+1 (A and B).
    int aOff[2], ldsA[2], bOff[2], ldsB[2];
    #pragma unroll
    for (int p = 0; p < 2; ++p) {
        int c = w * 2 + p;
        int phys = c * 1024 + lane * 16;
        int lgc = phys ^ (((phys >> 7) & 3) << 4);
        aOff[p] = (mBase + (lgc >> 6)) * K + ((lgc & 63) >> 1);
        bOff[p] = (nBase + (lgc >> 6)) * K + ((lgc & 63) >> 1);
        ldsA[p] = c * 512;
        ldsB[p] = c * 512;
    }

    const int kq = lane >> 4, rm = lane & 15;
    const int slot = kq ^ ((rm >> 1) & 3);

    v4f acc[4][4];
    #pragma unroll
    for (int i = 0; i < 4; ++i)
        #pragma unroll
        for (int j = 0; j < 4; ++j)
            acc[i][j] = (v4f){0.f, 0.f, 0.f, 0.f};

    auto stage = [&](int kt, int s) {
        const int ko = kt * 32;
        #pragma unroll
        for (int p = 0; p < 2; ++p) {
            GLL16(Ah + aOff[p] + ko, &AsH[s][ldsA[p]]);
            GLL16(Al + aOff[p] + ko, &AsL[s][ldsA[p]]);
            GLL16(Bh + bOff[p] + ko, &BsH[s][ldsB[p]]);
        }
    };
    stage(0, 0);
    stage(1, 1);      // 12 loads in flight

    for (int kt = 0; kt < KT; ++kt) {
        const int cs = kt & 1;
        if (kt < KT - 1) { WAIT_VM(6); } else { WAIT_VM(0); }
        SBAR(); SCHED();

        v8h ah[4], al[4], bh[4];
        #pragma unroll
        for (int i = 0; i < 4; ++i) {
            int rA = (wm * 64 + i * 16 + rm) * 32 + slot * 8;
            ah[i] = *(const v8h*)&AsH[cs][rA];
            al[i] = *(const v8h*)&AsL[cs][rA];
        }
        #pragma unroll
        for (int j = 0; j < 4; ++j) {
            int rB = (wn * 64 + j * 16 + rm) * 32 + slot * 8;
            bh[j] = *(const v8h*)&BsH[cs][rB];
        }
        #pragma unroll
        for (int i = 0; i < 4; ++i)
            #pragma unroll
            for (int j = 0; j < 4; ++j) {
                acc[i][j] = __builtin_amdgcn_mfma_f32_16x16x32_f16(
                    ah[i], bh[j], acc[i][j], 0, 0, 0);
                acc[i][j] = __builtin_amdgcn_mfma_f32_16x16x32_f16(
                    al[i], bh[j], acc[i][j], 0, 0, 0);
            }

        WAIT_LGKM0();
        SBAR(); SCHED();
        if (kt + 2 < KT) stage(kt + 2, cs);
    }

    const int rq = lane >> 4, cn = lane & 15;
    #pragma unroll
    for (int i = 0; i < 4; ++i)
        #pragma unroll
        for (int rg = 0; rg < 4; ++rg) {
            int row = mBase + wm * 64 + i * 16 + rq * 4 + rg;
            float sc = bn_g[row] * rsqrtf(bn_v[row] + 1e-5f);
            float sh = bn_b[row] - bn_m[row] * sc;
            #pragma unroll
            for (int j = 0; j < 4; ++j) {
                int col = nBase + wn * 64 + j * 16 + cn;
                C[(size_t)row * N + col] = acc[i][j][rg] * sc + sh;
            }
        }
}

// ---------------------------------------------------------------------------
// fp32 -> (fp16 hi, fp16 lo) for BOTH weight tensors in one launch.
// ---------------------------------------------------------------------------
__global__ __launch_bounds__(256) void cvt_split2(
    const float* __restrict__ s1, f16* __restrict__ d1h, f16* __restrict__ d1l,
    int n4_1,
    const float* __restrict__ s2, f16* __restrict__ d2h, f16* __restrict__ d2l,
    int n4_2)
{
    int i = blockIdx.x * 256 + threadIdx.x;
    const float* src; f16* dh; f16* dl; int idx;
    if (i < n4_1) { src = s1; dh = d1h; dl = d1l; idx = i; }
    else if (i < n4_1 + n4_2) { src = s2; dh = d2h; dl = d2l; idx = i - n4_1; }
    else return;
    float4 f = ((const float4*)src)[idx];
    f16 h[4], l[4];
    float ff[4] = {f.x, f.y, f.z, f.w};
    #pragma unroll
    for (int q = 0; q < 4; ++q) {
        h[q] = (f16)ff[q];
        l[q] = (f16)(ff[q] - (float)h[q]);
    }
    *(uint2*)&dh[(size_t)idx * 4] = *(uint2*)h;
    *(uint2*)&dl[(size_t)idx * 4] = *(uint2*)l;
}

// ---------------------------------------------------------------------------
// Transpose + split: x (b, c=512, n=4096) fp32 -> x_t_h/l (b, n, c) fp16.
// ---------------------------------------------------------------------------
__global__ __launch_bounds__(256) void transp_split(
    const float* __restrict__ src, f16* __restrict__ dh, f16* __restrict__ dl)
{
    __shared__ float t[64][65];
    const int tid = threadIdx.x;
    const int n0 = blockIdx.x * 64, c0 = blockIdx.y * 64, b = blockIdx.z;

    const int row = tid >> 2;
    const int nn  = (tid & 3) * 16;
    const float* sp = src + ((size_t)b * 512 + c0 + row) * NPIX + n0 + nn;
    #pragma unroll
    for (int q = 0; q < 4; ++q) {
        float4 f = *(const float4*)(sp + q * 4);
        t[row][nn + q * 4 + 0] = f.x;
        t[row][nn + q * 4 + 1] = f.y;
        t[row][nn + q * 4 + 2] = f.z;
        t[row][nn + q * 4 + 3] = f.w;
    }
    __syncthreads();

    const int nrow = tid >> 2;
    const int cc   = (tid & 3) * 16;
    f16 h[16], l[16];
    #pragma unroll
    for (int q = 0; q < 16; ++q) {
        float f = t[cc + q][nrow];
        h[q] = (f16)f;
        l[q] = (f16)(f - (float)h[q]);
    }
    size_t di = ((size_t)b * NPIX + n0 + nrow) * 512 + c0 + cc;
    *(uint4*)&dh[di] = *(uint4*)&h[0];
    *(uint4*)&dh[di + 8] = *(uint4*)&h[8];
    *(uint4*)&dl[di] = *(uint4*)&l[0];
    *(uint4*)&dl[di + 8] = *(uint4*)&l[8];
}

// ---------------------------------------------------------------------------
// Fused depthwise 5x5 conv (pad 2) + per-group 8x8 mix. (v2, proven)
// ---------------------------------------------------------------------------
__global__ __launch_bounds__(256) void dwpw(
    const float* __restrict__ qkv, const float* __restrict__ w_dw,
    const float* __restrict__ w_pw, float* __restrict__ y)
{
    __shared__ float tile[8][36][68];   // 78336 B -> 2 blocks/CU

    const int tid = threadIdx.x;
    const int g = blockIdx.y;
    const int b = blockIdx.z;
    const int h0 = blockIdx.x * 32;
    const size_t cbase = (size_t)b * TD3 + g * 8;

    for (int idx = tid; idx < 288; idx += 256) {
        int ch = idx / 36, r = idx - ch * 36;
        *(float2*)&tile[ch][r][0]  = (float2){0.f, 0.f};
        *(float2*)&tile[ch][r][66] = (float2){0.f, 0.f};
    }
    #pragma unroll
    for (int it = 0; it < 18; ++it) {
        int idx = tid + it * 256;
        int ch = idx / 576;
        int rem = idx - ch * 576;
        int r = rem >> 4, q = rem & 15;
        int gh = h0 + r - 2;
        float4 v = {0.f, 0.f, 0.f, 0.f};
        if (gh >= 0 && gh < 64)
            v = *(const float4*)&qkv[(cbase + ch) * NPIX + gh * 64 + q * 4];
        *(float2*)&tile[ch][r][2 + q * 4] = (float2){v.x, v.y};
        *(float2*)&tile[ch][r][4 + q * 4] = (float2){v.z, v.w};
    }
    __syncthreads();

    const int wc0 = (tid & 15) * 4;
    const int rp  = tid >> 4;

    float acc[8][8];
    #pragma unroll
    for (int o = 0; o < 8; ++o)
        #pragma unroll
        for (int p = 0; p < 8; ++p) acc[o][p] = 0.f;

    #pragma unroll
    for (int ch = 0; ch < 8; ++ch) {
        const float* wdg = w_dw + (size_t)(g * 8 + ch) * 25;
        float wdr[25];
        #pragma unroll
        for (int t = 0; t < 25; ++t) wdr[t] = wdg[t];
        float wpr[8];
        #pragma unroll
        for (int o = 0; o < 8; ++o) wpr[o] = w_pw[g * 64 + o * 8 + ch];

        float w[6][8];
        #pragma unroll
        for (int rr = 0; rr < 6; ++rr) {
            *(float4*)&w[rr][0] = *(const float4*)&tile[ch][rp * 2 + rr][wc0];
            *(float4*)&w[rr][4] = *(const float4*)&tile[ch][rp * 2 + rr][wc0 + 4];
        }

        float dwv[8];
        #pragma unroll
        for (int s = 0; s < 2; ++s)
            #pragma unroll
            for (int cc = 0; cc < 4; ++cc) {
                float sum = 0.f;
                #pragma unroll
                for (int di = 0; di < 5; ++di)
                    #pragma unroll
                    for (int dj = 0; dj < 5; ++dj)
                        sum = fmaf(w[s + di][cc + dj], wdr[di * 5 + dj], sum);
                dwv[s * 4 + cc] = sum;
            }
        #pragma unroll
        for (int o = 0; o < 8; ++o)
            #pragma unroll
            for (int p = 0; p < 8; ++p)
                acc[o][p] = fmaf(dwv[p], wpr[o], acc[o][p]);
    }

    #pragma unroll
    for (int o = 0; o < 8; ++o)
        #pragma unroll
        for (int s = 0; s < 2; ++s) {
            float4 v = {acc[o][s * 4 + 0], acc[o][s * 4 + 1],
                        acc[o][s * 4 + 2], acc[o][s * 4 + 3]};
            *(float4*)&y[(cbase + o) * NPIX + (h0 + rp * 2 + s) * 64 + wc0] = v;
        }
}

// ---------------------------------------------------------------------------
// Attention stats per (b,h): vk[9][8] = sum_n [v;1][d,n] * relu(k)[e,n]
// ---------------------------------------------------------------------------
__global__ __launch_bounds__(256) void attn_stats(
    const float* __restrict__ qkv, const float* __restrict__ yy,
    float* __restrict__ vkout)
{
    const int h = blockIdx.x;
    const int b = blockIdx.y;
    const float* src = (h < 64)
        ? qkv + ((size_t)b * TD3 + h * 24) * NPIX
        : yy  + ((size_t)b * TD3 + (h - 64) * 24) * NPIX;

    float acc[9][8];
    #pragma unroll
    for (int d = 0; d < 9; ++d)
        #pragma unroll
        for (int e = 0; e < 8; ++e) acc[d][e] = 0.f;

    for (int n = threadIdx.x; n < NPIX; n += 256) {
        float kr[8], vv[8];
        #pragma unroll
        for (int e = 0; e < 8; ++e) kr[e] = fmaxf(src[(8 + e) * NPIX + n], 0.f);
        #pragma unroll
        for (int d = 0; d < 8; ++d) vv[d] = src[(16 + d) * NPIX + n];
        #pragma unroll
        for (int d = 0; d < 8; ++d)
            #pragma unroll
            for (int e = 0; e < 8; ++e) acc[d][e] = fmaf(vv[d], kr[e], acc[d][e]);
        #pragma unroll
        for (int e = 0; e < 8; ++e) acc[8][e] += kr[e];
    }

    __shared__ float part[4][72];
    const int lane = threadIdx.x & 63, wave = threadIdx.x >> 6;
    #pragma unroll
    for (int i = 0; i < 72; ++i) {
        float v = acc[i / 8][i % 8];
        #pragma unroll
        for (int off = 32; off; off >>= 1) v += __shfl_down(v, off, 64);
        if (lane == 0) part[wave][i] = v;
    }
    __syncthreads();
    if (threadIdx.x < 72) {
        float v = part[0][threadIdx.x] + part[1][threadIdx.x] +
                  part[2][threadIdx.x] + part[3][threadIdx.x];
        vkout[((size_t)b * 128 + h) * 72 + threadIdx.x] = v;
    }
}

// ---------------------------------------------------------------------------
// Attention apply -> fp16, written transposed: attout[(b*4096+n)*1024+h*8+d]
// ---------------------------------------------------------------------------
__global__ __launch_bounds__(256) void attn_apply_t(
    const float* __restrict__ qkv, const float* __restrict__ yy,
    const float* __restrict__ vkin, f16* __restrict__ attout)
{
    const int h = blockIdx.y;
    const int b = blockIdx.z;
    const int n = blockIdx.x * 256 + threadIdx.x;

    __shared__ float vk[72];
    if (threadIdx.x < 72)
        vk[threadIdx.x] = vkin[((size_t)b * 128 + h) * 72 + threadIdx.x];
    __syncthreads();

    const float* src = (h < 64)
        ? qkv + ((size_t)b * TD3 + h * 24) * NPIX
        : yy  + ((size_t)b * TD3 + (h - 64) * 24) * NPIX;

    float qr[8];
    #pragma unroll
    for (int e = 0; e < 8; ++e) qr[e] = fmaxf(src[e * NPIX + n], 0.f);

    float den = 0.f;
    #pragma unroll
    for (int e = 0; e < 8; ++e) den = fmaf(vk[64 + e], qr[e], den);
    float inv = 1.f / (den + 1e-15f);

    f16 o[8];
    #pragma unroll
    for (int d = 0; d < 8; ++d) {
        float num = 0.f;
        #pragma unroll
        for (int e = 0; e < 8; ++e) num = fmaf(vk[d * 8 + e], qr[e], num);
        o[d] = (f16)(num * inv);
    }
    *(uint4*)&attout[((size_t)b * NPIX + n) * 1024 + h * 8] = *(uint4*)o;
}

// ---------------------------------------------------------------------------
extern "C" void kernel_launch(void* const* d_in, const int* in_sizes, int n_in,
                              void* d_out, int out_size, void* d_ws, size_t ws_size,
                              hipStream_t stream)
{
    (void)in_sizes; (void)n_in; (void)out_size; (void)ws_size;
    const float* x      = (const float*)d_in[0];
    const float* w_qkv  = (const float*)d_in[1];
    const float* w_dw   = (const float*)d_in[2];
    const float* w_pw   = (const float*)d_in[3];
    const float* w_proj = (const float*)d_in[4];
    const float* bn_g   = (const float*)d_in[5];
    const float* bn_b   = (const float*)d_in[6];
    const float* bn_m   = (const float*)d_in[7];
    const float* bn_v   = (const float*)d_in[8];
    float* out = (float*)d_out;

    char* ws = (char*)d_ws;
    float* qkv     = (float*)(ws);
    float* y       = (float*)(ws + 100663296);
    f16*   x_t_h   = (f16*)(ws + 201326592);    // dead after qkv GEMM
    f16*   x_t_l   = (f16*)(ws + 218103808);    // dead after qkv GEMM
    f16*   attout  = (f16*)(ws + 201326592);    // overlays x_t_h/l
    f16*   w_qkv_h = (f16*)(ws + 234881024);
    f16*   w_qkv_l = (f16*)(ws + 236453888);
    f16*   w_proj_h= (f16*)(ws + 238026752);
    f16*   w_proj_l= (f16*)(ws + 239075328);
    float* vk      = out;                        // scratch; proj overwrites

    // 0. split both weight tensors to fp16 hi/lo (one launch)
    cvt_split2<<<1280, 256, 0, stream>>>(
        w_qkv, w_qkv_h, w_qkv_l, 196608,
        w_proj, w_proj_h, w_proj_l, 131072);
    // 1. x (b,c,n) -> x_t (b,n,c) fp16 hi/lo
    transp_split<<<dim3(64, 8, 4), 256, 0, stream>>>(x, x_t_h, x_t_l);
    // 2. qkv = w_qkv @ x  (M=1536,N=4096,K=512, batch 4), 3-pass split
    gemm_qkv<<<dim3(32, 8, 4), 256, 0, stream>>>(
        w_qkv_h, w_qkv_l, x_t_h, x_t_l, qkv);
    // 3. y = groupmix(dwconv5x5(qkv)), 32-row tiles
    dwpw<<<dim3(2, 192, 4), 256, 0, stream>>>(qkv, w_dw, w_pw, y);
    // 4. attention stats -> vk (in d_out)
    attn_stats<<<dim3(128, 4), 256, 0, stream>>>(qkv, y, vk);
    // 5. attention apply -> attout (b,n,c) fp16 (overwrites dead x_t region)
    attn_apply_t<<<dim3(16, 128, 4), 256, 0, stream>>>(qkv, y, vk, attout);
    // 6. out = BN(w_proj @ attout)  (M=512,N=4096,K=1024, batch 4), 2-pass
    gemm_proj<<<dim3(32, 4, 4), 256, 0, stream>>>(
        w_proj_h, w_proj_l, attout, out, bn_g, bn_b, bn_m, bn_v);
}